// Round 3
// baseline (2622.645 us; speedup 1.0000x reference)
//
#include <hip/hip_runtime.h>
#include <hip/hip_cooperative_groups.h>
#include <math.h>

namespace cgrp = cooperative_groups;

// Problem constants
#define NS   4
#define CIN  64
#define COUT 4
#define HH   96
#define WW   96
#define HWSZ 9216
#define DS   5
#define KD   1600
#define ITER 20

static __device__ __forceinline__ float waveAllSum(float v) {
#pragma unroll
  for (int off = 32; off; off >>= 1) v += __shfl_xor(v, off);
  return v;
}

static __device__ __forceinline__ float4 f4add(float4 a, float4 b) {
  return make_float4(a.x + b.x, a.y + b.y, a.z + b.z, a.w + b.w);
}
static __device__ __forceinline__ float4 f4sub(float4 a, float4 b) {
  return make_float4(a.x - b.x, a.y - b.y, a.z - b.z, a.w - b.w);
}
static __device__ __forceinline__ float4 f4mul(float4 a, float4 b) {
  return make_float4(a.x * b.x, a.y * b.y, a.z * b.z, a.w * b.w);
}
static __device__ __forceinline__ float4 f4div(float4 a, float4 b) {
  return make_float4(a.x / b.x, a.y / b.y, a.z / b.z, a.w / b.w);
}
static __device__ __forceinline__ float4 f4fma(float4 a, float4 b, float4 c) {
  return make_float4(fmaf(a.x, b.x, c.x), fmaf(a.y, b.y, c.y),
                     fmaf(a.z, b.z, c.z), fmaf(a.w, b.w, c.w));
}
static __device__ __forceinline__ float f4sel(float4 v, int c) {
  return c == 0 ? v.x : c == 1 ? v.y : c == 2 ? v.z : v.w;
}

// ---------------- corr kernel v3: LDS-free ----------------
// corr[n,c1,c2,du,dv] = sum_{h,w} x1[h,w] * xpad2[h+du, w+dv], xpad = 4-pad.
// Wave w owns du in {3w..3w+2}; lane = 8 col-groups (12 cols) x 8 row-bands
// (12 rows). x2 window [12g, 12g+20) read directly from global (L1/L2-hot);
// validity boundaries (xpad cols [4,100), rows [4,100)) are 4-dword aligned,
// so each float4 chunk is entirely valid or entirely zero.

template<int SMOD3, bool J0, bool J1, bool J2, bool LOADROW>
static __device__ __forceinline__ void corr_step(
    int s, int h0, int d0, int w0,
    const float* __restrict__ x1g, const float* __restrict__ x2g,
    float (&x1w)[3][12], float (&acc)[27]) {
  int hp = h0 + d0 + s;        // xpad row
  int hr = hp - 4;             // x2 row
  bool rok = (hr >= 0) && (hr < 96);
  const float* rowp = x2g + hr * 96 + w0 - 4;   // xpad col (w0+k) -> x2 col w0+k-4
  float xr[20];
#pragma unroll
  for (int t = 0; t < 5; ++t) {
    int c0 = w0 + 4 * t;       // xpad col of this chunk
    float4 v = make_float4(0.f, 0.f, 0.f, 0.f);
    if (rok && (c0 >= 4) && (c0 < 100)) v = *(const float4*)(rowp + 4 * t);
    *(float4*)&xr[4 * t] = v;
  }
  if (LOADROW) {
    const float4* xrow = (const float4*)(x1g + (h0 + s) * 96 + w0);
    *(float4*)&x1w[SMOD3][0] = xrow[0];
    *(float4*)&x1w[SMOD3][4] = xrow[1];
    *(float4*)&x1w[SMOD3][8] = xrow[2];
  }
  if (J0) {   // du-offset j=0, x1 row = s, slot SMOD3
#pragma unroll
    for (int c = 0; c < 12; ++c)
#pragma unroll
      for (int dv = 0; dv < 9; ++dv)
        acc[0 * 9 + dv] += x1w[SMOD3][c] * xr[c + dv];
  }
  if (J1) {   // j=1, x1 row = s-1
#pragma unroll
    for (int c = 0; c < 12; ++c)
#pragma unroll
      for (int dv = 0; dv < 9; ++dv)
        acc[1 * 9 + dv] += x1w[(SMOD3 + 2) % 3][c] * xr[c + dv];
  }
  if (J2) {   // j=2, x1 row = s-2
#pragma unroll
    for (int c = 0; c < 12; ++c)
#pragma unroll
      for (int dv = 0; dv < 9; ++dv)
        acc[2 * 9 + dv] += x1w[(SMOD3 + 1) % 3][c] * xr[c + dv];
  }
}

__global__ __launch_bounds__(192, 3) void corr_kernel(const float* __restrict__ xs,
                                                      float* __restrict__ corr) {
  // compact triangular grid: 4 * 2080 blocks, pair (c1<=c2)
  int pid = blockIdx.x;
  int n = pid / 2080;
  int t = pid - n * 2080;
  int c1 = (int)((129.0f - sqrtf((float)(16641 - 8 * t))) * 0.5f);
  while (c1 > 0 && (c1 * (129 - c1)) / 2 > t) --c1;
  while (((c1 + 1) * (128 - c1)) / 2 <= t) ++c1;
  int c2 = c1 + (t - (c1 * (129 - c1)) / 2);

  const float* x1g = xs + (size_t)(n * CIN + c1) * HWSZ;
  const float* x2g = xs + (size_t)(n * CIN + c2) * HWSZ;

  int tid = threadIdx.x;
  int wid = tid >> 6, lane = tid & 63;
  int g = lane & 7, band = lane >> 3;
  int w0 = 12 * g, h0 = 12 * band, d0 = 3 * wid;

  float acc[27];
#pragma unroll
  for (int k = 0; k < 27; ++k) acc[k] = 0.f;
  float x1w[3][12];

  corr_step<0, true, false, false, true>(0, h0, d0, w0, x1g, x2g, x1w, acc);
  corr_step<1, true, true,  false, true>(1, h0, d0, w0, x1g, x2g, x1w, acc);
  for (int sb = 2; sb <= 8; sb += 3) {   // s = 2..10
    corr_step<2, true, true, true, true>(sb,     h0, d0, w0, x1g, x2g, x1w, acc);
    corr_step<0, true, true, true, true>(sb + 1, h0, d0, w0, x1g, x2g, x1w, acc);
    corr_step<1, true, true, true, true>(sb + 2, h0, d0, w0, x1g, x2g, x1w, acc);
  }
  corr_step<2, true,  true, true, true >(11, h0, d0, w0, x1g, x2g, x1w, acc);
  corr_step<0, false, true, true, false>(12, h0, d0, w0, x1g, x2g, x1w, acc);
  corr_step<1, false, false, true, false>(13, h0, d0, w0, x1g, x2g, x1w, acc);

  // wave-internal full reduction (each wave fully owns its 3 du values)
#pragma unroll
  for (int k = 0; k < 27; ++k) {
    float v = acc[k];
#pragma unroll
    for (int off = 1; off < 64; off <<= 1) v += __shfl_xor(v, off);
    acc[k] = v;
  }
  if (lane == 0) {
    size_t pbase = ((size_t)((n * CIN + c1) * CIN + c2)) * 81;
#pragma unroll
    for (int k = 0; k < 27; ++k) {
      int du = d0 + k / 9, dvv = k % 9;
      corr[pbase + du * 9 + dvv] = acc[k];
    }
    if (c1 != c2) {
      size_t mbase = ((size_t)((n * CIN + c2) * CIN + c1)) * 81;
#pragma unroll
      for (int k = 0; k < 27; ++k) {
        int du = d0 + k / 9, dvv = k % 9;
        corr[mbase + (8 - du) * 9 + (8 - dvv)] = acc[k];
      }
    }
  }
}

// ---------------- xty kernel (unchanged) ----------------
__global__ __launch_bounds__(256) void xty_kernel(const float* __restrict__ xs,
                                                  const float* __restrict__ ys,
                                                  const float* __restrict__ dd,
                                                  const float* __restrict__ alpha,
                                                  const float* __restrict__ reg,
                                                  float* __restrict__ P) {
  int bid = blockIdx.x;          // ((n*CIN)+c)*COUT + b
  int b = bid & 3;
  int c = (bid >> 2) & 63;
  int n = bid >> 8;
  __shared__ float xp[100 * 100];
  __shared__ float redbuf[4][25];
  const float* xg = xs + (size_t)(n * CIN + c) * HWSZ;
  const float* yg = ys + (size_t)(n * COUT + b) * HWSZ;
  int tid = threadIdx.x;
  for (int i = tid; i < 100 * 100; i += 256) xp[i] = 0.f;
  __syncthreads();
  for (int i = tid; i < HWSZ; i += 256) {
    int h = i / 96, w = i - h * 96;
    xp[(h + 2) * 100 + (w + 2)] = xg[i];
  }
  __syncthreads();

  float acc[25];
#pragma unroll
  for (int k = 0; k < 25; ++k) acc[k] = 0.f;
  int tx = tid & 31, ty = tid >> 5;
  int w0 = tx * 3;
  for (int h = ty; h < 96; h += 8) {
    float y0 = yg[h * 96 + w0];
    float y1 = yg[h * 96 + w0 + 1];
    float y2 = yg[h * 96 + w0 + 2];
#pragma unroll
    for (int u = 0; u < 5; ++u) {
      const float* rowp = &xp[(h + u) * 100 + w0];
      float rbuf[7];
#pragma unroll
      for (int j = 0; j < 7; ++j) rbuf[j] = rowp[j];
#pragma unroll
      for (int v = 0; v < 5; ++v) {
        acc[u * 5 + v] += y0 * rbuf[v] + y1 * rbuf[v + 1] + y2 * rbuf[v + 2];
      }
    }
  }
  int wave = tid >> 6, lane = tid & 63;
#pragma unroll
  for (int k = 0; k < 25; ++k) {
    float s = waveAllSum(acc[k]);
    if (lane == 0) redbuf[wave][k] = s;
  }
  __syncthreads();
  if (tid < 25) {
    float tot = redbuf[0][tid] + redbuf[1][tid] + redbuf[2][tid] + redbuf[3][tid];
    float a = alpha[n] * reg[0] * ((float)(HH * WW) / (float)(DS * DS * CIN));
    float dv = dd[((size_t)(n * COUT + b) * CIN + c) * 25 + tid];
    P[((size_t)(n * KD) + c * 25 + tid) * COUT + b] = tot + a * dv;
  }
}

// ---------------- cooperative CG: whole solve in one kernel ----------------
// 256 blocks = (n, c1). Each block keeps FULL r, p (and its own-row x) in
// registers, redundantly and identically across blocks (deterministic, no
// atomics). corrS + creg staged once for all iterations. Per iter: matvec on
// own 25 rows -> write W + pAp partials -> grid.sync -> fixed-order partial
// sum -> redundant vector updates. W/pAp double-buffered by iter parity.

static __device__ __forceinline__ float4 allreduce1_f4(float4 a, float4* redA, int tid) {
#pragma unroll
  for (int off = 1; off < 64; off <<= 1) {
    a.x += __shfl_xor(a.x, off); a.y += __shfl_xor(a.y, off);
    a.z += __shfl_xor(a.z, off); a.w += __shfl_xor(a.w, off);
  }
  int wid = tid >> 6;
  if ((tid & 63) == 0) redA[wid] = a;
  __syncthreads();
  float4 s = f4add(f4add(redA[0], redA[1]), f4add(redA[2], redA[3]));
  __syncthreads();
  return s;
}

__global__ __launch_bounds__(256, 1) void cg_coop_kernel(
    const float* __restrict__ corr, const float* __restrict__ P,
    float* __restrict__ W0g, float* __restrict__ W1g,
    float* __restrict__ pp0, float* __restrict__ pp1,
    const float* __restrict__ ralpha, const float* __restrict__ rreg,
    float* __restrict__ out) {
  __shared__ float corrS[64 * 84];
  __shared__ float4 pS[KD];
  __shared__ float4 redA[4];
  __shared__ float redW[4][25][4];
  __shared__ float redP[25][4];

  int blk = blockIdx.x;
  int n = blk >> 6, c1 = blk & 63;
  int tid = threadIdx.x;
  int lo = c1 * 25;
  float aa = ralpha[n] * rreg[0] * ((float)(HH * WW) / (float)(DS * DS * CIN));

  // stage corr slab [c2][81] once
  const float* cgp = corr + ((size_t)(n * CIN + c1)) * CIN * 81;
  for (int i = tid; i < 5184; i += 256) corrS[(i / 81) * 84 + (i % 81)] = cgp[i];
  __syncthreads();

  // persistent per-thread corr row (thread = c2*4 + col)
  int c2 = tid >> 2, col = tid & 3;
  float creg[81];
#pragma unroll
  for (int t4 = 0; t4 < 20; ++t4)
    *(float4*)&creg[4 * t4] = *(const float4*)&corrS[c2 * 84 + 4 * t4];
  creg[80] = corrS[c2 * 84 + 80];

  const float4 zero4 = make_float4(0.f, 0.f, 0.f, 0.f);
  const float4* P4 = (const float4*)P + (size_t)n * KD;
  float4 rv[7], pv[7];
  bool okv[7], ownv[7];
  float4 rho = zero4;
#pragma unroll
  for (int s = 0; s < 7; ++s) {
    int idx = tid + 256 * s;
    okv[s] = idx < KD;
    ownv[s] = (idx >= lo) && (idx < lo + 25);
    rv[s] = okv[s] ? P4[idx] : zero4;
    pv[s] = rv[s];
    rho = f4fma(rv[s], rv[s], rho);
  }
  rho = allreduce1_f4(rho, redA, tid);
  float4 xown = zero4;

  for (int k = 0; k < ITER; ++k) {
    float* Wg  = (k & 1) ? W1g : W0g;
    float* ppg = (k & 1) ? pp1 : pp0;

    __syncthreads();
#pragma unroll
    for (int s = 0; s < 7; ++s) {
      int idx = tid + 256 * s;
      if (okv[s]) pS[idx] = pv[s];
    }
    __syncthreads();

    // matvec for own 25 rows
    float a25[25];
#pragma unroll
    for (int i = 0; i < 25; ++i) a25[i] = 0.f;
#pragma unroll
    for (int j = 0; j < 25; ++j) {
      float4 pj = pS[c2 * 25 + j];
      float pvv = f4sel(pj, col);
#pragma unroll
      for (int i = 0; i < 25; ++i) {
        const int i1 = i / 5, i2 = i % 5, j1 = j / 5, j2 = j % 5;
        a25[i] += creg[(j1 - i1 + 4) * 9 + (j2 - i2 + 4)] * pvv;
      }
    }
#pragma unroll
    for (int i = 0; i < 25; ++i) {
      float v = a25[i];
      v += __shfl_xor(v, 4); v += __shfl_xor(v, 8);
      v += __shfl_xor(v, 16); v += __shfl_xor(v, 32);
      a25[i] = v;
    }
    int wid = tid >> 6;
    if ((tid & 63) < 4) {
#pragma unroll
      for (int i = 0; i < 25; ++i) redW[wid][i][col] = a25[i];
    }
    __syncthreads();
    if (tid < 100) {
      int i = tid >> 2, cc = tid & 3;
      float wval = redW[0][i][cc] + redW[1][i][cc] + redW[2][i][cc] + redW[3][i][cc];
      float pown = f4sel(pS[lo + i], cc);
      wval = fmaf(aa, pown, wval);
      Wg[((size_t)n * KD + lo + i) * 4 + cc] = wval;
      redP[i][cc] = wval * pown;
    }
    __syncthreads();
    if (tid < 4) {
      float s = 0.f;
      for (int i = 0; i < 25; ++i) s += redP[i][tid];
      ppg[(size_t)(n * 64 + c1) * 4 + tid] = s;
    }
    __threadfence();
    cgrp::this_grid().sync();

    // global pAp: fixed-order sum of 64 partials (identical in all blocks)
    float4 pAp = zero4;
    const float4* pp4 = (const float4*)ppg + (size_t)n * 64;
    for (int c = 0; c < 64; ++c) pAp = f4add(pAp, pp4[c]);
    float4 av = f4div(rho, pAp);

    const float4* Wg4 = (const float4*)Wg + (size_t)n * KD;
    float4 rho1 = zero4;
#pragma unroll
    for (int s = 0; s < 7; ++s) {
      if (okv[s]) {
        int idx = tid + 256 * s;
        float4 wt = Wg4[idx];
        rv[s] = f4sub(rv[s], f4mul(av, wt));
        rho1 = f4fma(rv[s], rv[s], rho1);
        if (ownv[s]) xown = f4fma(av, pv[s], xown);
      }
    }
    rho1 = allreduce1_f4(rho1, redA, tid);
    float4 bv = f4div(rho1, rho);
    rho = rho1;
#pragma unroll
    for (int s = 0; s < 7; ++s) pv[s] = f4fma(bv, pv[s], rv[s]);
  }

  // write own rows, transposed: out[n, col, c1, i]
  __syncthreads();
#pragma unroll
  for (int s = 0; s < 7; ++s) {
    int idx = tid + 256 * s;
    if (ownv[s]) pS[idx - lo] = xown;
  }
  __syncthreads();
  if (tid < 100) {
    int i = tid >> 2, cc = tid & 3;
    float xv = f4sel(pS[i], cc);
    out[((size_t)(n * 4 + cc) * 64 + c1) * 25 + i] = xv;
  }
}

extern "C" void kernel_launch(void* const* d_in, const int* in_sizes, int n_in,
                              void* d_out, int out_size, void* d_ws, size_t ws_size,
                              hipStream_t stream) {
  (void)in_sizes; (void)n_in; (void)out_size; (void)ws_size;
  const float* xs    = (const float*)d_in[0];   // [4,1,64,96,96]
  const float* dd    = (const float*)d_in[1];   // [4,4,64,5,5]
  const float* ys    = (const float*)d_in[2];   // [4,4,1,96,96]
  const float* alpha = (const float*)d_in[3];   // [4]
  const float* reg   = (const float*)d_in[4];   // [1]
  float* out = (float*)d_out;
  float* ws  = (float*)d_ws;

  const size_t SZ_CORR = (size_t)NS * CIN * CIN * 81;   // 1,327,104
  const size_t SZ_V    = (size_t)NS * KD * COUT;        // 25,600
  float* corr = ws;
  float* P    = corr + SZ_CORR;
  float* W0   = P + SZ_V;
  float* W1   = W0 + SZ_V;
  float* pp0  = W1 + SZ_V;
  float* pp1  = pp0 + (size_t)NS * 64 * 4;

  corr_kernel<<<NS * 2080, 192, 0, stream>>>(xs, corr);
  xty_kernel<<<NS * CIN * COUT, 256, 0, stream>>>(xs, ys, dd, alpha, reg, P);

  void* args[] = {(void*)&corr, (void*)&P, (void*)&W0, (void*)&W1,
                  (void*)&pp0, (void*)&pp1, (void*)&alpha, (void*)&reg, (void*)&out};
  hipLaunchCooperativeKernel((const void*)cg_coop_kernel, dim3(NS * CIN), dim3(256),
                             args, 0, stream);
}

// Round 4
// 355.183 us; speedup vs baseline: 7.3839x; 7.3839x over previous
//
#include <hip/hip_runtime.h>
#include <math.h>

// Problem constants
#define NS   4
#define CIN  64
#define COUT 4
#define HH   96
#define WW   96
#define HWSZ 9216
#define DS   5
#define KD   1600
#define ITER 12

static __device__ __forceinline__ float waveAllSum(float v) {
#pragma unroll
  for (int off = 32; off; off >>= 1) v += __shfl_xor(v, off);
  return v;
}

static __device__ __forceinline__ float4 f4add(float4 a, float4 b) {
  return make_float4(a.x + b.x, a.y + b.y, a.z + b.z, a.w + b.w);
}
static __device__ __forceinline__ float4 f4sub(float4 a, float4 b) {
  return make_float4(a.x - b.x, a.y - b.y, a.z - b.z, a.w - b.w);
}
static __device__ __forceinline__ float4 f4mul(float4 a, float4 b) {
  return make_float4(a.x * b.x, a.y * b.y, a.z * b.z, a.w * b.w);
}
static __device__ __forceinline__ float4 f4div(float4 a, float4 b) {
  return make_float4(a.x / b.x, a.y / b.y, a.z / b.z, a.w / b.w);
}
static __device__ __forceinline__ float4 f4fma(float4 a, float4 b, float4 c) {
  return make_float4(fmaf(a.x, b.x, c.x), fmaf(a.y, b.y, c.y),
                     fmaf(a.z, b.z, c.z), fmaf(a.w, b.w, c.w));
}
static __device__ __forceinline__ float f4sel(float4 v, int c) {
  return c == 0 ? v.x : c == 1 ? v.y : c == 2 ? v.z : v.w;
}

// RNE-pack two floats to bf16 pair in a u32 (elem0 low, elem1 high)
static __device__ __forceinline__ unsigned int pack2bf(float a, float b) {
  unsigned int ua = __float_as_uint(a);
  ua = (ua + 0x7fffu + ((ua >> 16) & 1u)) >> 16;
  unsigned int ub = __float_as_uint(b);
  ub = (ub + 0x7fffu + ((ub >> 16) & 1u)) & 0xffff0000u;
  return ua | ub;
}

// ---------------- corr kernel v4: bf16 LDS staging ----------------
// corr[n,c1,c2,du,dv] = sum_{h,w} x1[h,w] * x2pad[h+du, w+dv]  (4-pad).
// Wave wid owns du in {3wid..3wid+2}; lane = 8 col-groups (12 cols) x 8
// row-bands (12 rows). x2pad stored bf16 in LDS, rows of 108 elems (104
// used); per step 6x ds_read_b64 (24 bf16) unpacked to fp32. x1 fp32 from
// global (L2-hot). 3-row x1 register window shares loads across the 3 du.

template<int SMOD3, bool J0, bool J1, bool J2, bool LOADROW>
static __device__ __forceinline__ void corr_step(
    int s, int h0, int d0, int w0,
    const float* __restrict__ x1g, const unsigned short* __restrict__ x2b,
    float (&x1w)[3][12], float (&acc)[27]) {
  int hp = h0 + d0 + s;        // xpad row, 0..103
  const uint2* rp = (const uint2*)(x2b + hp * 108 + w0);   // 8B aligned (w0=12g)
  float xr[24];
#pragma unroll
  for (int t = 0; t < 6; ++t) {
    uint2 u = rp[t];
    xr[4 * t + 0] = __uint_as_float(u.x << 16);
    xr[4 * t + 1] = __uint_as_float(u.x & 0xffff0000u);
    xr[4 * t + 2] = __uint_as_float(u.y << 16);
    xr[4 * t + 3] = __uint_as_float(u.y & 0xffff0000u);
  }
  if (LOADROW) {
    const float4* xrow = (const float4*)(x1g + (h0 + s) * 96 + w0);
    *(float4*)&x1w[SMOD3][0] = xrow[0];
    *(float4*)&x1w[SMOD3][4] = xrow[1];
    *(float4*)&x1w[SMOD3][8] = xrow[2];
  }
  if (J0) {   // du-offset j=0, x1 row = s, slot SMOD3
#pragma unroll
    for (int c = 0; c < 12; ++c)
#pragma unroll
      for (int dv = 0; dv < 9; ++dv)
        acc[0 * 9 + dv] += x1w[SMOD3][c] * xr[c + dv];
  }
  if (J1) {   // j=1, x1 row = s-1
#pragma unroll
    for (int c = 0; c < 12; ++c)
#pragma unroll
      for (int dv = 0; dv < 9; ++dv)
        acc[1 * 9 + dv] += x1w[(SMOD3 + 2) % 3][c] * xr[c + dv];
  }
  if (J2) {   // j=2, x1 row = s-2
#pragma unroll
    for (int c = 0; c < 12; ++c)
#pragma unroll
      for (int dv = 0; dv < 9; ++dv)
        acc[2 * 9 + dv] += x1w[(SMOD3 + 1) % 3][c] * xr[c + dv];
  }
}

__global__ __launch_bounds__(192, 4) void corr_kernel(const float* __restrict__ xs,
                                                      float* __restrict__ corr) {
  // compact triangular grid: 4 * 2080 blocks, pair (c1<=c2)
  int pid = blockIdx.x;
  int n = pid / 2080;
  int t = pid - n * 2080;
  int c1 = (int)((129.0f - sqrtf((float)(16641 - 8 * t))) * 0.5f);
  while (c1 > 0 && (c1 * (129 - c1)) / 2 > t) --c1;
  while (((c1 + 1) * (128 - c1)) / 2 <= t) ++c1;
  int c2 = c1 + (t - (c1 * (129 - c1)) / 2);

  __shared__ unsigned short x2b[104 * 108];   // 22464 B, bf16 padded image
  int tid = threadIdx.x;
  const float* x1g = xs + (size_t)(n * CIN + c1) * HWSZ;
  const float* x2g = xs + (size_t)(n * CIN + c2) * HWSZ;

  unsigned int* zp = (unsigned int*)x2b;
  for (int i = tid; i < 5616; i += 192) zp[i] = 0u;
  __syncthreads();
  for (int i = tid; i < 2304; i += 192) {
    int h = i / 24, c4 = i - h * 24;
    float4 v = ((const float4*)x2g)[h * 24 + c4];
    uint2 pk;
    pk.x = pack2bf(v.x, v.y);
    pk.y = pack2bf(v.z, v.w);
    *(uint2*)(x2b + (h + 4) * 108 + 4 + 4 * c4) = pk;
  }
  __syncthreads();

  int wid = tid >> 6, lane = tid & 63;
  int g = lane & 7, band = lane >> 3;
  int w0 = 12 * g, h0 = 12 * band, d0 = 3 * wid;

  float acc[27];
#pragma unroll
  for (int k = 0; k < 27; ++k) acc[k] = 0.f;
  float x1w[3][12];

  corr_step<0, true, false, false, true>(0, h0, d0, w0, x1g, x2b, x1w, acc);
  corr_step<1, true, true,  false, true>(1, h0, d0, w0, x1g, x2b, x1w, acc);
  for (int sb = 2; sb <= 8; sb += 3) {   // s = 2..10
    corr_step<2, true, true, true, true>(sb,     h0, d0, w0, x1g, x2b, x1w, acc);
    corr_step<0, true, true, true, true>(sb + 1, h0, d0, w0, x1g, x2b, x1w, acc);
    corr_step<1, true, true, true, true>(sb + 2, h0, d0, w0, x1g, x2b, x1w, acc);
  }
  corr_step<2, true,  true, true, true >(11, h0, d0, w0, x1g, x2b, x1w, acc);
  corr_step<0, false, true, true, false>(12, h0, d0, w0, x1g, x2b, x1w, acc);
  corr_step<1, false, false, true, false>(13, h0, d0, w0, x1g, x2b, x1w, acc);

  // wave-internal full reduction (each wave fully owns its 3 du values)
#pragma unroll
  for (int k = 0; k < 27; ++k) {
    float v = acc[k];
#pragma unroll
    for (int off = 1; off < 64; off <<= 1) v += __shfl_xor(v, off);
    acc[k] = v;
  }
  if (lane == 0) {
    size_t pbase = ((size_t)((n * CIN + c1) * CIN + c2)) * 81;
#pragma unroll
    for (int k = 0; k < 27; ++k) {
      int du = d0 + k / 9, dvv = k % 9;
      corr[pbase + du * 9 + dvv] = acc[k];
    }
    if (c1 != c2) {
      size_t mbase = ((size_t)((n * CIN + c2) * CIN + c1)) * 81;
#pragma unroll
      for (int k = 0; k < 27; ++k) {
        int du = d0 + k / 9, dvv = k % 9;
        corr[mbase + (8 - du) * 9 + (8 - dvv)] = acc[k];
      }
    }
  }
}

// ---------------- xty kernel (round-2 version, proven) ----------------
__global__ __launch_bounds__(256) void xty_kernel(const float* __restrict__ xs,
                                                  const float* __restrict__ ys,
                                                  const float* __restrict__ dd,
                                                  const float* __restrict__ alpha,
                                                  const float* __restrict__ reg,
                                                  float* __restrict__ P) {
  int bid = blockIdx.x;          // ((n*CIN)+c)*COUT + b
  int b = bid & 3;
  int c = (bid >> 2) & 63;
  int n = bid >> 8;
  __shared__ float xp[100 * 100];
  __shared__ float redbuf[4][25];
  const float* xg = xs + (size_t)(n * CIN + c) * HWSZ;
  const float* yg = ys + (size_t)(n * COUT + b) * HWSZ;
  int tid = threadIdx.x;
  for (int i = tid; i < 100 * 100; i += 256) xp[i] = 0.f;
  __syncthreads();
  for (int i = tid; i < HWSZ; i += 256) {
    int h = i / 96, w = i - h * 96;
    xp[(h + 2) * 100 + (w + 2)] = xg[i];
  }
  __syncthreads();

  float acc[25];
#pragma unroll
  for (int k = 0; k < 25; ++k) acc[k] = 0.f;
  int tx = tid & 31, ty = tid >> 5;
  int w0 = tx * 3;
  for (int h = ty; h < 96; h += 8) {
    float y0 = yg[h * 96 + w0];
    float y1 = yg[h * 96 + w0 + 1];
    float y2 = yg[h * 96 + w0 + 2];
#pragma unroll
    for (int u = 0; u < 5; ++u) {
      const float* rowp = &xp[(h + u) * 100 + w0];
      float rbuf[7];
#pragma unroll
      for (int j = 0; j < 7; ++j) rbuf[j] = rowp[j];
#pragma unroll
      for (int v = 0; v < 5; ++v) {
        acc[u * 5 + v] += y0 * rbuf[v] + y1 * rbuf[v + 1] + y2 * rbuf[v + 2];
      }
    }
  }
  int wave = tid >> 6, lane = tid & 63;
#pragma unroll
  for (int k = 0; k < 25; ++k) {
    float s = waveAllSum(acc[k]);
    if (lane == 0) redbuf[wave][k] = s;
  }
  __syncthreads();
  if (tid < 25) {
    float tot = redbuf[0][tid] + redbuf[1][tid] + redbuf[2][tid] + redbuf[3][tid];
    float a = alpha[n] * reg[0] * ((float)(HH * WW) / (float)(DS * DS * CIN));
    float dv = dd[((size_t)(n * COUT + b) * CIN + c) * 25 + tid];
    P[((size_t)(n * KD) + c * 25 + tid) * COUT + b] = tot + a * dv;
  }
}

// ---------------- fused CG iteration (round-2 version, proven) ----------------
static __device__ __forceinline__ void allreduce2_f4(float4& a, float4& b,
                                                     float4* redA, float4* redB, int tid) {
#pragma unroll
  for (int off = 1; off < 64; off <<= 1) {
    a.x += __shfl_xor(a.x, off); a.y += __shfl_xor(a.y, off);
    a.z += __shfl_xor(a.z, off); a.w += __shfl_xor(a.w, off);
    b.x += __shfl_xor(b.x, off); b.y += __shfl_xor(b.y, off);
    b.z += __shfl_xor(b.z, off); b.w += __shfl_xor(b.w, off);
  }
  int wid = tid >> 6;
  if ((tid & 63) == 0) { redA[wid] = a; redB[wid] = b; }
  __syncthreads();
  float4 sa = f4add(f4add(redA[0], redA[1]), f4add(redA[2], redA[3]));
  float4 sb = f4add(f4add(redB[0], redB[1]), f4add(redB[2], redB[3]));
  __syncthreads();
  a = sa; b = sb;
}

__global__ __launch_bounds__(256) void cg_iter_kernel(
    const float* __restrict__ corr, const float* __restrict__ P,
    const float* __restrict__ Rin, float* __restrict__ Rout,
    const float* __restrict__ Win, float* __restrict__ Wout,
    const float* __restrict__ PFin, float* __restrict__ PFout,
    float* __restrict__ X,
    const float* __restrict__ ralpha, const float* __restrict__ rreg,
    int first) {
  __shared__ float corrS[64 * 84];
  __shared__ float4 pS[KD];
  __shared__ float4 redA[4], redB[4];
  __shared__ float redW[4][25][4];

  int b = blockIdx.x;
  int n = b >> 6, c1 = b & 63;
  int tid = threadIdx.x;

  const float* cgp = corr + ((size_t)(n * CIN + c1)) * CIN * 81;
  for (int i = tid; i < 5184; i += 256) corrS[(i / 81) * 84 + (i % 81)] = cgp[i];

  const float4* Rin4 = (const float4*)Rin + (size_t)n * KD;
  const float4* Win4 = (const float4*)Win + (size_t)n * KD;
  const float4* PFin4 = (const float4*)PFin + (size_t)n * KD;
  const float4* P4 = (const float4*)P + (size_t)n * KD;
  float4* Rout4 = (float4*)Rout + (size_t)n * KD;
  float4* PFout4 = (float4*)PFout + (size_t)n * KD;
  float4* X4 = (float4*)X + (size_t)n * KD;

  const float4 zero4 = make_float4(0.f, 0.f, 0.f, 0.f);
  float4 rv[7], wv[7], pv[7];
#pragma unroll
  for (int t = 0; t < 7; ++t) {
    int idx = tid + 256 * t;
    bool ok = idx < KD;
    if (first) {
      rv[t] = ok ? P4[idx] : zero4;
      wv[t] = zero4; pv[t] = zero4;
    } else {
      rv[t] = ok ? Rin4[idx] : zero4;
      wv[t] = ok ? Win4[idx] : zero4;
      pv[t] = ok ? PFin4[idx] : zero4;
    }
  }
  float4 rho_prev = zero4, pAp = zero4;
#pragma unroll
  for (int t = 0; t < 7; ++t) {
    rho_prev = f4fma(rv[t], rv[t], rho_prev);
    pAp = f4fma(pv[t], wv[t], pAp);
  }
  allreduce2_f4(rho_prev, pAp, redA, redB, tid);

  float4 av = first ? zero4 : f4div(rho_prev, pAp);   // alpha_{k-1}

  float4 rho_k = zero4;
#pragma unroll
  for (int t = 0; t < 7; ++t) {
    rv[t] = f4sub(rv[t], f4mul(av, wv[t]));
    rho_k = f4fma(rv[t], rv[t], rho_k);
  }
  int lo = c1 * 25;
#pragma unroll
  for (int t = 0; t < 7; ++t) {
    int idx = tid + 256 * t;
    if (idx >= lo && idx < lo + 25) {
      if (first) X4[idx] = zero4;
      else X4[idx] = f4fma(av, pv[t], X4[idx]);
    }
  }
  float4 dummy = zero4;
  allreduce2_f4(rho_k, dummy, redA, redB, tid);

  float4 bv = first ? zero4 : f4div(rho_k, rho_prev);

#pragma unroll
  for (int t = 0; t < 7; ++t) {
    int idx = tid + 256 * t;
    if (idx < KD) {
      float4 pnew = f4fma(bv, pv[t], rv[t]);
      pS[idx] = pnew;
      if (idx >= lo && idx < lo + 25) {
        PFout4[idx] = pnew;
        Rout4[idx] = rv[t];
      }
    }
  }
  __syncthreads();

  int c2 = tid >> 2, col = tid & 3;
  float creg[81];
#pragma unroll
  for (int t4 = 0; t4 < 20; ++t4)
    *(float4*)&creg[4 * t4] = *(const float4*)&corrS[c2 * 84 + 4 * t4];
  creg[80] = corrS[c2 * 84 + 80];

  float a25[25];
#pragma unroll
  for (int i = 0; i < 25; ++i) a25[i] = 0.f;
  const float* pSf = (const float*)pS;
#pragma unroll
  for (int j = 0; j < 25; ++j) {
    float pvv = pSf[(c2 * 25 + j) * 4 + col];
#pragma unroll
    for (int i = 0; i < 25; ++i) {
      const int i1 = i / 5, i2 = i % 5, j1 = j / 5, j2 = j % 5;
      a25[i] += creg[(j1 - i1 + 4) * 9 + (j2 - i2 + 4)] * pvv;
    }
  }
#pragma unroll
  for (int i = 0; i < 25; ++i) {
    float v = a25[i];
    v += __shfl_xor(v, 4); v += __shfl_xor(v, 8);
    v += __shfl_xor(v, 16); v += __shfl_xor(v, 32);
    a25[i] = v;
  }
  int wid = tid >> 6;
  if ((tid & 63) < 4) {
#pragma unroll
    for (int i = 0; i < 25; ++i) redW[wid][i][col] = a25[i];
  }
  __syncthreads();
  if (tid < 100) {
    int i = tid >> 2, cc = tid & 3;
    float wval = redW[0][i][cc] + redW[1][i][cc] + redW[2][i][cc] + redW[3][i][cc];
    float aa = ralpha[n] * rreg[0] * ((float)(HH * WW) / (float)(DS * DS * CIN));
    int row = lo + i;
    wval = fmaf(aa, pSf[row * 4 + cc], wval);
    Wout[((size_t)n * KD + row) * 4 + cc] = wval;
  }
}

// ---------------- finalize ----------------
__global__ __launch_bounds__(256) void cg_final_kernel(
    const float* __restrict__ Rin, const float* __restrict__ Win,
    const float* __restrict__ PFin, const float* __restrict__ X,
    float* __restrict__ out) {
  __shared__ float4 redA[4], redB[4];
  int b = blockIdx.x;
  int n = b >> 6, c1 = b & 63;
  int tid = threadIdx.x;

  const float4* Rin4 = (const float4*)Rin + (size_t)n * KD;
  const float4* Win4 = (const float4*)Win + (size_t)n * KD;
  const float4* PFin4 = (const float4*)PFin + (size_t)n * KD;
  const float4 zero4 = make_float4(0.f, 0.f, 0.f, 0.f);

  float4 rho = zero4, pAp = zero4;
#pragma unroll
  for (int t = 0; t < 7; ++t) {
    int idx = tid + 256 * t;
    if (idx < KD) {
      float4 r = Rin4[idx], w = Win4[idx], p = PFin4[idx];
      rho = f4fma(r, r, rho);
      pAp = f4fma(p, w, pAp);
    }
  }
  allreduce2_f4(rho, pAp, redA, redB, tid);
  float4 av = f4div(rho, pAp);

  if (tid < 100) {
    int i = tid >> 2, cc = tid & 3;
    int row = c1 * 25 + i;
    float a_cc = f4sel(av, cc);
    float xv = X[((size_t)n * KD + row) * 4 + cc] + a_cc * PFin[((size_t)n * KD + row) * 4 + cc];
    out[((size_t)(n * 4 + cc) * 64 + c1) * 25 + i] = xv;
  }
}

extern "C" void kernel_launch(void* const* d_in, const int* in_sizes, int n_in,
                              void* d_out, int out_size, void* d_ws, size_t ws_size,
                              hipStream_t stream) {
  (void)in_sizes; (void)n_in; (void)out_size; (void)ws_size;
  const float* xs    = (const float*)d_in[0];   // [4,1,64,96,96]
  const float* dd    = (const float*)d_in[1];   // [4,4,64,5,5]
  const float* ys    = (const float*)d_in[2];   // [4,4,1,96,96]
  const float* alpha = (const float*)d_in[3];   // [4]
  const float* reg   = (const float*)d_in[4];   // [1]
  float* out = (float*)d_out;
  float* ws  = (float*)d_ws;

  const size_t SZ_CORR = (size_t)NS * CIN * CIN * 81;   // 1,327,104
  const size_t SZ_V    = (size_t)NS * KD * COUT;        // 25,600
  float* corr = ws;
  float* P    = corr + SZ_CORR;
  float* X    = P + SZ_V;
  float* R0   = X + SZ_V;
  float* R1   = R0 + SZ_V;
  float* W0   = R1 + SZ_V;
  float* W1   = W0 + SZ_V;
  float* PF0  = W1 + SZ_V;
  float* PF1  = PF0 + SZ_V;
  float* Rb[2] = {R0, R1};
  float* Wb[2] = {W0, W1};
  float* Pb[2] = {PF0, PF1};

  corr_kernel<<<NS * 2080, 192, 0, stream>>>(xs, corr);
  xty_kernel<<<NS * CIN * COUT, 256, 0, stream>>>(xs, ys, dd, alpha, reg, P);
  for (int k = 0; k < ITER; ++k) {
    cg_iter_kernel<<<NS * CIN, 256, 0, stream>>>(
        corr, P,
        Rb[k & 1], Rb[(k + 1) & 1],
        Wb[k & 1], Wb[(k + 1) & 1],
        Pb[k & 1], Pb[(k + 1) & 1],
        X, alpha, reg, k == 0 ? 1 : 0);
  }
  // ITER even -> last iteration wrote parity 0
  cg_final_kernel<<<NS * CIN, 256, 0, stream>>>(Rb[0], Wb[0], Pb[0], X, out);
}

// Round 5
// 278.129 us; speedup vs baseline: 9.4296x; 1.2770x over previous
//
#include <hip/hip_runtime.h>
#include <math.h>

// Problem constants
#define NS   4
#define CIN  64
#define COUT 4
#define HH   96
#define WW   96
#define HWSZ 9216
#define DS   5
#define KD   1600
#define ITER 10

#ifndef __has_builtin
#define __has_builtin(x) 0
#endif
#if __has_builtin(__builtin_amdgcn_fdot2)
#define USE_FDOT2 1
#else
#define USE_FDOT2 0
#endif

typedef _Float16 h2 __attribute__((ext_vector_type(2)));

static __device__ __forceinline__ float waveAllSum(float v) {
#pragma unroll
  for (int off = 32; off; off >>= 1) v += __shfl_xor(v, off);
  return v;
}

static __device__ __forceinline__ float4 f4add(float4 a, float4 b) {
  return make_float4(a.x + b.x, a.y + b.y, a.z + b.z, a.w + b.w);
}
static __device__ __forceinline__ float4 f4sub(float4 a, float4 b) {
  return make_float4(a.x - b.x, a.y - b.y, a.z - b.z, a.w - b.w);
}
static __device__ __forceinline__ float4 f4mul(float4 a, float4 b) {
  return make_float4(a.x * b.x, a.y * b.y, a.z * b.z, a.w * b.w);
}
static __device__ __forceinline__ float4 f4div(float4 a, float4 b) {
  return make_float4(a.x / b.x, a.y / b.y, a.z / b.z, a.w / b.w);
}
static __device__ __forceinline__ float4 f4fma(float4 a, float4 b, float4 c) {
  return make_float4(fmaf(a.x, b.x, c.x), fmaf(a.y, b.y, c.y),
                     fmaf(a.z, b.z, c.z), fmaf(a.w, b.w, c.w));
}
static __device__ __forceinline__ float f4sel(float4 v, int c) {
  return c == 0 ? v.x : c == 1 ? v.y : c == 2 ? v.z : v.w;
}

static __device__ __forceinline__ unsigned int packh2(float a, float b) {
  h2 h; h.x = (_Float16)a; h.y = (_Float16)b;
  return __builtin_bit_cast(unsigned int, h);
}
static __device__ __forceinline__ h2 ash2(unsigned int u) {
  return __builtin_bit_cast(h2, u);
}

// RNE-pack two floats to bf16 pair in a u32 (fallback path)
static __device__ __forceinline__ unsigned int pack2bf(float a, float b) {
  unsigned int ua = __float_as_uint(a);
  ua = (ua + 0x7fffu + ((ua >> 16) & 1u)) >> 16;
  unsigned int ub = __float_as_uint(b);
  ub = (ub + 0x7fffu + ((ub >> 16) & 1u)) & 0xffff0000u;
  return ua | ub;
}

// ---------------- corr kernel v5 ----------------
// corr[n,c1,c2,du,dv] = sum_{h,w} x1[h,w] * x2pad[h+du, w+dv]  (4-pad).
// Wave wid owns du in {3wid..3wid+2}; lane = 8 col-groups (12 cols) x 8
// row-bands (12 rows). x2pad staged f16 (RNE) in LDS, rows of 108 elems.
// Inner loop: v_dot2_f32_f16 (2 MACs/inst, fp32 accum); odd dv shifts via
// funnel-shifted dword copies (v_alignbit). x1 packed f16 once per row.

#if USE_FDOT2
template<int SMOD3, bool J0, bool J1, bool J2, bool LOADROW>
static __device__ __forceinline__ void corr_step(
    int s, int h0, int d0, int w0,
    const float* __restrict__ x1g, const unsigned short* __restrict__ x2h,
    unsigned int (&x1p)[3][6], float (&acc)[27]) {
  int hp = h0 + d0 + s;        // xpad row, 0..103
  const uint2* rp = (const uint2*)(x2h + hp * 108 + w0);   // 8B aligned
  unsigned int xr[12];
#pragma unroll
  for (int t = 0; t < 6; ++t) {
    uint2 u = rp[t];
    xr[2 * t] = u.x; xr[2 * t + 1] = u.y;
  }
  unsigned int xro[9];
#pragma unroll
  for (int k = 0; k < 9; ++k) xro[k] = (xr[k] >> 16) | (xr[k + 1] << 16);
  if (LOADROW) {
    const float4* xrow = (const float4*)(x1g + (h0 + s) * 96 + w0);
    float4 r0 = xrow[0], r1 = xrow[1], r2 = xrow[2];
    x1p[SMOD3][0] = packh2(r0.x, r0.y);
    x1p[SMOD3][1] = packh2(r0.z, r0.w);
    x1p[SMOD3][2] = packh2(r1.x, r1.y);
    x1p[SMOD3][3] = packh2(r1.z, r1.w);
    x1p[SMOD3][4] = packh2(r2.x, r2.y);
    x1p[SMOD3][5] = packh2(r2.z, r2.w);
  }
#define DOJ(JIDX, SLOT)                                                        \
  {                                                                            \
    _Pragma("unroll") for (int k = 0; k < 6; ++k) {                            \
      h2 a = ash2(x1p[SLOT][k]);                                               \
      _Pragma("unroll") for (int dv = 0; dv < 9; ++dv) {                       \
        unsigned int bw = (dv & 1) ? xro[k + (dv >> 1)] : xr[k + (dv >> 1)];   \
        acc[JIDX * 9 + dv] =                                                   \
            __builtin_amdgcn_fdot2(a, ash2(bw), acc[JIDX * 9 + dv], false);    \
      }                                                                        \
    }                                                                          \
  }
  if (J0) DOJ(0, SMOD3)
  if (J1) DOJ(1, (SMOD3 + 2) % 3)
  if (J2) DOJ(2, (SMOD3 + 1) % 3)
#undef DOJ
}
#else
template<int SMOD3, bool J0, bool J1, bool J2, bool LOADROW>
static __device__ __forceinline__ void corr_step(
    int s, int h0, int d0, int w0,
    const float* __restrict__ x1g, const unsigned short* __restrict__ x2b,
    float (&x1w)[3][12], float (&acc)[27]) {
  int hp = h0 + d0 + s;
  const uint2* rp = (const uint2*)(x2b + hp * 108 + w0);
  float xr[24];
#pragma unroll
  for (int t = 0; t < 6; ++t) {
    uint2 u = rp[t];
    xr[4 * t + 0] = __uint_as_float(u.x << 16);
    xr[4 * t + 1] = __uint_as_float(u.x & 0xffff0000u);
    xr[4 * t + 2] = __uint_as_float(u.y << 16);
    xr[4 * t + 3] = __uint_as_float(u.y & 0xffff0000u);
  }
  if (LOADROW) {
    const float4* xrow = (const float4*)(x1g + (h0 + s) * 96 + w0);
    *(float4*)&x1w[SMOD3][0] = xrow[0];
    *(float4*)&x1w[SMOD3][4] = xrow[1];
    *(float4*)&x1w[SMOD3][8] = xrow[2];
  }
  if (J0) {
#pragma unroll
    for (int c = 0; c < 12; ++c)
#pragma unroll
      for (int dv = 0; dv < 9; ++dv)
        acc[0 * 9 + dv] += x1w[SMOD3][c] * xr[c + dv];
  }
  if (J1) {
#pragma unroll
    for (int c = 0; c < 12; ++c)
#pragma unroll
      for (int dv = 0; dv < 9; ++dv)
        acc[1 * 9 + dv] += x1w[(SMOD3 + 2) % 3][c] * xr[c + dv];
  }
  if (J2) {
#pragma unroll
    for (int c = 0; c < 12; ++c)
#pragma unroll
      for (int dv = 0; dv < 9; ++dv)
        acc[2 * 9 + dv] += x1w[(SMOD3 + 1) % 3][c] * xr[c + dv];
  }
}
#endif

__global__ __launch_bounds__(192, 3) void corr_kernel(const float* __restrict__ xs,
                                                      float* __restrict__ corr) {
  // compact triangular grid: 4 * 2080 blocks, pair (c1<=c2)
  int pid = blockIdx.x;
  int n = pid / 2080;
  int t = pid - n * 2080;
  int c1 = (int)((129.0f - sqrtf((float)(16641 - 8 * t))) * 0.5f);
  while (c1 > 0 && (c1 * (129 - c1)) / 2 > t) --c1;
  while (((c1 + 1) * (128 - c1)) / 2 <= t) ++c1;
  int c2 = c1 + (t - (c1 * (129 - c1)) / 2);

  __shared__ unsigned short x2s[104 * 108];   // 22464 B, f16 (or bf16) padded image
  int tid = threadIdx.x;
  const float* x1g = xs + (size_t)(n * CIN + c1) * HWSZ;
  const float* x2g = xs + (size_t)(n * CIN + c2) * HWSZ;

  unsigned int* zp = (unsigned int*)x2s;
  for (int i = tid; i < 5616; i += 192) zp[i] = 0u;
  __syncthreads();
  for (int i = tid; i < 2304; i += 192) {
    int h = i / 24, c4 = i - h * 24;
    float4 v = ((const float4*)x2g)[h * 24 + c4];
    uint2 pk;
#if USE_FDOT2
    pk.x = packh2(v.x, v.y);
    pk.y = packh2(v.z, v.w);
#else
    pk.x = pack2bf(v.x, v.y);
    pk.y = pack2bf(v.z, v.w);
#endif
    *(uint2*)(x2s + (h + 4) * 108 + 4 + 4 * c4) = pk;
  }
  __syncthreads();

  int wid = tid >> 6, lane = tid & 63;
  int g = lane & 7, band = lane >> 3;
  int w0 = 12 * g, h0 = 12 * band, d0 = 3 * wid;

  float acc[27];
#pragma unroll
  for (int k = 0; k < 27; ++k) acc[k] = 0.f;
#if USE_FDOT2
  unsigned int x1v[3][6];
#else
  float x1v[3][12];
#endif

  corr_step<0, true, false, false, true>(0, h0, d0, w0, x1g, x2s, x1v, acc);
  corr_step<1, true, true,  false, true>(1, h0, d0, w0, x1g, x2s, x1v, acc);
  for (int sb = 2; sb <= 8; sb += 3) {   // s = 2..10
    corr_step<2, true, true, true, true>(sb,     h0, d0, w0, x1g, x2s, x1v, acc);
    corr_step<0, true, true, true, true>(sb + 1, h0, d0, w0, x1g, x2s, x1v, acc);
    corr_step<1, true, true, true, true>(sb + 2, h0, d0, w0, x1g, x2s, x1v, acc);
  }
  corr_step<2, true,  true, true, true >(11, h0, d0, w0, x1g, x2s, x1v, acc);
  corr_step<0, false, true, true, false>(12, h0, d0, w0, x1g, x2s, x1v, acc);
  corr_step<1, false, false, true, false>(13, h0, d0, w0, x1g, x2s, x1v, acc);

  // wave-internal full reduction (each wave fully owns its 3 du values)
#pragma unroll
  for (int k = 0; k < 27; ++k) {
    float v = acc[k];
#pragma unroll
    for (int off = 1; off < 64; off <<= 1) v += __shfl_xor(v, off);
    acc[k] = v;
  }
  if (lane == 0) {
    size_t pbase = ((size_t)((n * CIN + c1) * CIN + c2)) * 81;
#pragma unroll
    for (int k = 0; k < 27; ++k) {
      int du = d0 + k / 9, dvv = k % 9;
      corr[pbase + du * 9 + dvv] = acc[k];
    }
    if (c1 != c2) {
      size_t mbase = ((size_t)((n * CIN + c2) * CIN + c1)) * 81;
#pragma unroll
      for (int k = 0; k < 27; ++k) {
        int du = d0 + k / 9, dvv = k % 9;
        corr[mbase + (8 - du) * 9 + (8 - dvv)] = acc[k];
      }
    }
  }
}

// ---------------- xty kernel (proven) ----------------
__global__ __launch_bounds__(256) void xty_kernel(const float* __restrict__ xs,
                                                  const float* __restrict__ ys,
                                                  const float* __restrict__ dd,
                                                  const float* __restrict__ alpha,
                                                  const float* __restrict__ reg,
                                                  float* __restrict__ P) {
  int bid = blockIdx.x;          // ((n*CIN)+c)*COUT + b
  int b = bid & 3;
  int c = (bid >> 2) & 63;
  int n = bid >> 8;
  __shared__ float xp[100 * 100];
  __shared__ float redbuf[4][25];
  const float* xg = xs + (size_t)(n * CIN + c) * HWSZ;
  const float* yg = ys + (size_t)(n * COUT + b) * HWSZ;
  int tid = threadIdx.x;
  for (int i = tid; i < 100 * 100; i += 256) xp[i] = 0.f;
  __syncthreads();
  for (int i = tid; i < HWSZ; i += 256) {
    int h = i / 96, w = i - h * 96;
    xp[(h + 2) * 100 + (w + 2)] = xg[i];
  }
  __syncthreads();

  float acc[25];
#pragma unroll
  for (int k = 0; k < 25; ++k) acc[k] = 0.f;
  int tx = tid & 31, ty = tid >> 5;
  int w0 = tx * 3;
  for (int h = ty; h < 96; h += 8) {
    float y0 = yg[h * 96 + w0];
    float y1 = yg[h * 96 + w0 + 1];
    float y2 = yg[h * 96 + w0 + 2];
#pragma unroll
    for (int u = 0; u < 5; ++u) {
      const float* rowp = &xp[(h + u) * 100 + w0];
      float rbuf[7];
#pragma unroll
      for (int j = 0; j < 7; ++j) rbuf[j] = rowp[j];
#pragma unroll
      for (int v = 0; v < 5; ++v) {
        acc[u * 5 + v] += y0 * rbuf[v] + y1 * rbuf[v + 1] + y2 * rbuf[v + 2];
      }
    }
  }
  int wave = tid >> 6, lane = tid & 63;
#pragma unroll
  for (int k = 0; k < 25; ++k) {
    float s = waveAllSum(acc[k]);
    if (lane == 0) redbuf[wave][k] = s;
  }
  __syncthreads();
  if (tid < 25) {
    float tot = redbuf[0][tid] + redbuf[1][tid] + redbuf[2][tid] + redbuf[3][tid];
    float a = alpha[n] * reg[0] * ((float)(HH * WW) / (float)(DS * DS * CIN));
    float dv = dd[((size_t)(n * COUT + b) * CIN + c) * 25 + tid];
    P[((size_t)(n * KD) + c * 25 + tid) * COUT + b] = tot + a * dv;
  }
}

// ---------------- fused CG iteration (proven) ----------------
static __device__ __forceinline__ void allreduce2_f4(float4& a, float4& b,
                                                     float4* redA, float4* redB, int tid) {
#pragma unroll
  for (int off = 1; off < 64; off <<= 1) {
    a.x += __shfl_xor(a.x, off); a.y += __shfl_xor(a.y, off);
    a.z += __shfl_xor(a.z, off); a.w += __shfl_xor(a.w, off);
    b.x += __shfl_xor(b.x, off); b.y += __shfl_xor(b.y, off);
    b.z += __shfl_xor(b.z, off); b.w += __shfl_xor(b.w, off);
  }
  int wid = tid >> 6;
  if ((tid & 63) == 0) { redA[wid] = a; redB[wid] = b; }
  __syncthreads();
  float4 sa = f4add(f4add(redA[0], redA[1]), f4add(redA[2], redA[3]));
  float4 sb = f4add(f4add(redB[0], redB[1]), f4add(redB[2], redB[3]));
  __syncthreads();
  a = sa; b = sb;
}

__global__ __launch_bounds__(256) void cg_iter_kernel(
    const float* __restrict__ corr, const float* __restrict__ P,
    const float* __restrict__ Rin, float* __restrict__ Rout,
    const float* __restrict__ Win, float* __restrict__ Wout,
    const float* __restrict__ PFin, float* __restrict__ PFout,
    float* __restrict__ X,
    const float* __restrict__ ralpha, const float* __restrict__ rreg,
    int first) {
  __shared__ float corrS[64 * 84];
  __shared__ float4 pS[KD];
  __shared__ float4 redA[4], redB[4];
  __shared__ float redW[4][25][4];

  int b = blockIdx.x;
  int n = b >> 6, c1 = b & 63;
  int tid = threadIdx.x;

  const float* cgp = corr + ((size_t)(n * CIN + c1)) * CIN * 81;
  for (int i = tid; i < 5184; i += 256) corrS[(i / 81) * 84 + (i % 81)] = cgp[i];

  const float4* Rin4 = (const float4*)Rin + (size_t)n * KD;
  const float4* Win4 = (const float4*)Win + (size_t)n * KD;
  const float4* PFin4 = (const float4*)PFin + (size_t)n * KD;
  const float4* P4 = (const float4*)P + (size_t)n * KD;
  float4* Rout4 = (float4*)Rout + (size_t)n * KD;
  float4* PFout4 = (float4*)PFout + (size_t)n * KD;
  float4* X4 = (float4*)X + (size_t)n * KD;

  const float4 zero4 = make_float4(0.f, 0.f, 0.f, 0.f);
  float4 rv[7], wv[7], pv[7];
#pragma unroll
  for (int t = 0; t < 7; ++t) {
    int idx = tid + 256 * t;
    bool ok = idx < KD;
    if (first) {
      rv[t] = ok ? P4[idx] : zero4;
      wv[t] = zero4; pv[t] = zero4;
    } else {
      rv[t] = ok ? Rin4[idx] : zero4;
      wv[t] = ok ? Win4[idx] : zero4;
      pv[t] = ok ? PFin4[idx] : zero4;
    }
  }
  float4 rho_prev = zero4, pAp = zero4;
#pragma unroll
  for (int t = 0; t < 7; ++t) {
    rho_prev = f4fma(rv[t], rv[t], rho_prev);
    pAp = f4fma(pv[t], wv[t], pAp);
  }
  allreduce2_f4(rho_prev, pAp, redA, redB, tid);

  float4 av = first ? zero4 : f4div(rho_prev, pAp);   // alpha_{k-1}

  float4 rho_k = zero4;
#pragma unroll
  for (int t = 0; t < 7; ++t) {
    rv[t] = f4sub(rv[t], f4mul(av, wv[t]));
    rho_k = f4fma(rv[t], rv[t], rho_k);
  }
  int lo = c1 * 25;
#pragma unroll
  for (int t = 0; t < 7; ++t) {
    int idx = tid + 256 * t;
    if (idx >= lo && idx < lo + 25) {
      if (first) X4[idx] = zero4;
      else X4[idx] = f4fma(av, pv[t], X4[idx]);
    }
  }
  float4 dummy = zero4;
  allreduce2_f4(rho_k, dummy, redA, redB, tid);

  float4 bv = first ? zero4 : f4div(rho_k, rho_prev);

#pragma unroll
  for (int t = 0; t < 7; ++t) {
    int idx = tid + 256 * t;
    if (idx < KD) {
      float4 pnew = f4fma(bv, pv[t], rv[t]);
      pS[idx] = pnew;
      if (idx >= lo && idx < lo + 25) {
        PFout4[idx] = pnew;
        Rout4[idx] = rv[t];
      }
    }
  }
  __syncthreads();

  int c2 = tid >> 2, col = tid & 3;
  float creg[81];
#pragma unroll
  for (int t4 = 0; t4 < 20; ++t4)
    *(float4*)&creg[4 * t4] = *(const float4*)&corrS[c2 * 84 + 4 * t4];
  creg[80] = corrS[c2 * 84 + 80];

  float a25[25];
#pragma unroll
  for (int i = 0; i < 25; ++i) a25[i] = 0.f;
  const float* pSf = (const float*)pS;
#pragma unroll
  for (int j = 0; j < 25; ++j) {
    float pvv = pSf[(c2 * 25 + j) * 4 + col];
#pragma unroll
    for (int i = 0; i < 25; ++i) {
      const int i1 = i / 5, i2 = i % 5, j1 = j / 5, j2 = j % 5;
      a25[i] += creg[(j1 - i1 + 4) * 9 + (j2 - i2 + 4)] * pvv;
    }
  }
#pragma unroll
  for (int i = 0; i < 25; ++i) {
    float v = a25[i];
    v += __shfl_xor(v, 4); v += __shfl_xor(v, 8);
    v += __shfl_xor(v, 16); v += __shfl_xor(v, 32);
    a25[i] = v;
  }
  int wid = tid >> 6;
  if ((tid & 63) < 4) {
#pragma unroll
    for (int i = 0; i < 25; ++i) redW[wid][i][col] = a25[i];
  }
  __syncthreads();
  if (tid < 100) {
    int i = tid >> 2, cc = tid & 3;
    float wval = redW[0][i][cc] + redW[1][i][cc] + redW[2][i][cc] + redW[3][i][cc];
    float aa = ralpha[n] * rreg[0] * ((float)(HH * WW) / (float)(DS * DS * CIN));
    int row = lo + i;
    wval = fmaf(aa, pSf[row * 4 + cc], wval);
    Wout[((size_t)n * KD + row) * 4 + cc] = wval;
  }
}

// ---------------- finalize ----------------
__global__ __launch_bounds__(256) void cg_final_kernel(
    const float* __restrict__ Rin, const float* __restrict__ Win,
    const float* __restrict__ PFin, const float* __restrict__ X,
    float* __restrict__ out) {
  __shared__ float4 redA[4], redB[4];
  int b = blockIdx.x;
  int n = b >> 6, c1 = b & 63;
  int tid = threadIdx.x;

  const float4* Rin4 = (const float4*)Rin + (size_t)n * KD;
  const float4* Win4 = (const float4*)Win + (size_t)n * KD;
  const float4* PFin4 = (const float4*)PFin + (size_t)n * KD;
  const float4 zero4 = make_float4(0.f, 0.f, 0.f, 0.f);

  float4 rho = zero4, pAp = zero4;
#pragma unroll
  for (int t = 0; t < 7; ++t) {
    int idx = tid + 256 * t;
    if (idx < KD) {
      float4 r = Rin4[idx], w = Win4[idx], p = PFin4[idx];
      rho = f4fma(r, r, rho);
      pAp = f4fma(p, w, pAp);
    }
  }
  allreduce2_f4(rho, pAp, redA, redB, tid);
  float4 av = f4div(rho, pAp);

  if (tid < 100) {
    int i = tid >> 2, cc = tid & 3;
    int row = c1 * 25 + i;
    float a_cc = f4sel(av, cc);
    float xv = X[((size_t)n * KD + row) * 4 + cc] + a_cc * PFin[((size_t)n * KD + row) * 4 + cc];
    out[((size_t)(n * 4 + cc) * 64 + c1) * 25 + i] = xv;
  }
}

extern "C" void kernel_launch(void* const* d_in, const int* in_sizes, int n_in,
                              void* d_out, int out_size, void* d_ws, size_t ws_size,
                              hipStream_t stream) {
  (void)in_sizes; (void)n_in; (void)out_size; (void)ws_size;
  const float* xs    = (const float*)d_in[0];   // [4,1,64,96,96]
  const float* dd    = (const float*)d_in[1];   // [4,4,64,5,5]
  const float* ys    = (const float*)d_in[2];   // [4,4,1,96,96]
  const float* alpha = (const float*)d_in[3];   // [4]
  const float* reg   = (const float*)d_in[4];   // [1]
  float* out = (float*)d_out;
  float* ws  = (float*)d_ws;

  const size_t SZ_CORR = (size_t)NS * CIN * CIN * 81;   // 1,327,104
  const size_t SZ_V    = (size_t)NS * KD * COUT;        // 25,600
  float* corr = ws;
  float* P    = corr + SZ_CORR;
  float* X    = P + SZ_V;
  float* R0   = X + SZ_V;
  float* R1   = R0 + SZ_V;
  float* W0   = R1 + SZ_V;
  float* W1   = W0 + SZ_V;
  float* PF0  = W1 + SZ_V;
  float* PF1  = PF0 + SZ_V;
  float* Rb[2] = {R0, R1};
  float* Wb[2] = {W0, W1};
  float* Pb[2] = {PF0, PF1};

  corr_kernel<<<NS * 2080, 192, 0, stream>>>(xs, corr);
  xty_kernel<<<NS * CIN * COUT, 256, 0, stream>>>(xs, ys, dd, alpha, reg, P);
  for (int k = 0; k < ITER; ++k) {
    cg_iter_kernel<<<NS * CIN, 256, 0, stream>>>(
        corr, P,
        Rb[k & 1], Rb[(k + 1) & 1],
        Wb[k & 1], Wb[(k + 1) & 1],
        Pb[k & 1], Pb[(k + 1) & 1],
        X, alpha, reg, k == 0 ? 1 : 0);
  }
  // ITER even -> last iteration wrote parity 0
  cg_final_kernel<<<NS * CIN, 256, 0, stream>>>(Rb[0], Wb[0], Pb[0], X, out);
}

// Round 7
// 270.161 us; speedup vs baseline: 9.7077x; 1.0295x over previous
//
#include <hip/hip_runtime.h>

// Problem constants
#define NS   4
#define CIN  64
#define COUT 4
#define HH   96
#define WW   96
#define HWSZ 9216
#define DS   5
#define KD   1600
#define ITER 9

// Padded f16 image geometry
#define ROWF 120                    // f16 per padded row
#define ROWB 240                    // bytes per padded row (15 x 16B chunks)
#define CHB  (96*ROWB)              // channel stride bytes (23040)
#define IMGB ((size_t)64*CHB)       // per-sample bytes
#define XSB  ((size_t)256*CHB)      // per-shift-buffer bytes (4 samples x 64 ch)
#define CORR_RS 84                  // corr row stride in floats (81 used, 16B-aligned)

typedef _Float16 f16_t;
typedef _Float16 f16x8_t __attribute__((ext_vector_type(8)));
typedef float    f32x16_t __attribute__((ext_vector_type(16)));

static __device__ __forceinline__ void gll16(const void* g, void* l) {
  __builtin_amdgcn_global_load_lds((const __attribute__((address_space(1))) unsigned int*)g,
                                   (__attribute__((address_space(3))) unsigned int*)l, 16, 0, 0);
}

static __device__ __forceinline__ float waveAllSum(float v) {
#pragma unroll
  for (int off = 32; off; off >>= 1) v += __shfl_xor(v, off);
  return v;
}
static __device__ __forceinline__ float4 f4add(float4 a, float4 b) {
  return make_float4(a.x + b.x, a.y + b.y, a.z + b.z, a.w + b.w);
}
static __device__ __forceinline__ float4 f4sub(float4 a, float4 b) {
  return make_float4(a.x - b.x, a.y - b.y, a.z - b.z, a.w - b.w);
}
static __device__ __forceinline__ float4 f4mul(float4 a, float4 b) {
  return make_float4(a.x * b.x, a.y * b.y, a.z * b.z, a.w * b.w);
}
static __device__ __forceinline__ float4 f4div(float4 a, float4 b) {
  return make_float4(a.x / b.x, a.y / b.y, a.z / b.z, a.w / b.w);
}
static __device__ __forceinline__ float4 f4fma(float4 a, float4 b, float4 c) {
  return make_float4(fmaf(a.x, b.x, c.x), fmaf(a.y, b.y, c.y),
                     fmaf(a.z, b.z, c.z), fmaf(a.w, b.w, c.w));
}
static __device__ __forceinline__ float f4sel(float4 v, int c) {
  return c == 0 ? v.x : c == 1 ? v.y : c == 2 ? v.z : v.w;
}

// ---------------- convert: xs fp32 -> 5 shifted padded f16 images ----------------
// XS_s[c][r][i] = x[c][r][i-8+s] for (i-8+s) in [0,96), else 0;  s in 0..4.
// Row = 120 f16 (240 B = 15 x 16B chunks). No out-of-row reads ever needed later.
__global__ __launch_bounds__(256) void convert_kernel(const float* __restrict__ xs,
                                                      unsigned int* __restrict__ XS32) {
  const int PERBUF = 256 * 96 * 60;          // uint (f16-pair) writes per buffer
  int idx = blockIdx.x * 256 + threadIdx.x;
  if (idx >= 5 * PERBUF) return;
  int s = idx / PERBUF;
  int rr = idx - s * PERBUF;
  int p = rr % 60; int t = rr / 60;
  int r = t % 96;  int c = t / 96;
  const float* row = xs + (size_t)c * HWSZ + r * 96;
  int lo = 8 - s;                            // first valid padded index
  int i0 = 2 * p, i1 = i0 + 1;
  float f0 = (i0 >= lo && i0 < lo + 96) ? row[i0 - lo] : 0.f;
  float f1 = (i1 >= lo && i1 < lo + 96) ? row[i1 - lo] : 0.f;
  f16_t h0 = (f16_t)f0, h1 = (f16_t)f1;
  unsigned int pk = (unsigned int)__builtin_bit_cast(unsigned short, h0)
                  | ((unsigned int)__builtin_bit_cast(unsigned short, h1) << 16);
  XS32[(size_t)s * PERBUF + (size_t)c * (96 * 60) + r * 60 + p] = pk;
}

// ---------------- corr via MFMA ----------------
// Block = (n, shift pair). Representatives: dv in 5..8 x du 0..8 (36) plus dv=4 x du 0..4 (41).
// corr[n,c1,c2,du,dv] = sum_{h,w} x1[c1][h][w] * x2[c2][h+du-4][w+dv-4] (zero outside).
// A rows from XS_0 (x1[k] = XS0[8+k]); B rows from XS_{dv-4} (x2[k+dv-4] = XS_{dv-4}[8+k]).
// All staging: global_load_lds 16B from 16B-aligned row bases (no byte shifts, no guards).
// 2 waves; wave r computes row pair element r; full 64x64 via 2x2 mfma_f32_32x32x16_f16.
// Epilogue: cross-wave sum in LDS, write main + mirror (8-du,8-dv) slices.
__global__ __launch_bounds__(128) void corr_mfma_kernel(const unsigned short* __restrict__ XS,
                                                        float* __restrict__ corrP) {
  __shared__ __align__(16) unsigned char Ash[2 * 64 * ROWB];   // 30720 B
  __shared__ __align__(16) unsigned char Bsh[2 * 64 * ROWB];   // 30720 B
  int bid = blockIdx.x;
  int n = bid / 41, p = bid % 41;
  int du, dv;
  if (p < 36) { du = p % 9; dv = 5 + p / 9; }
  else        { du = p - 36; dv = 4; }
  const char* An = (const char*)XS + (size_t)n * IMGB;                       // XS_0, sample n
  const char* Bn = (const char*)XS + (size_t)(dv - 4) * XSB + (size_t)n * IMGB;
  int tid = threadIdx.x, wid = tid >> 6, lane = tid & 63;
  int l5 = lane >> 5, l31 = lane & 31;
  int h0 = (du < 4) ? (4 - du) : 0;          // first valid x1 row
  int nR = (du < 4) ? (92 + du) : (100 - du);
  int steps = (nR + 1) >> 1;
  f32x16_t acc[2][2] = {};

  for (int s = 0; s < steps; ++s) {
    int rows = nR - 2 * s; if (rows > 2) rows = 2;
    int hA = h0 + 2 * s;
    int hB = hA + du - 4;
    __syncthreads();
    for (int r = 0; r < rows; ++r) {
      const char* arow = An + (size_t)(hA + r) * ROWB;
      const char* brow = Bn + (size_t)(hB + r) * ROWB;
      for (int ch = wid; ch < 15; ch += 2) {           // 64ch x 240B, 16B/lane, 15 groups
        int t16 = ch * 64 + lane;
        int c = t16 / 15, sub = t16 - c * 15;
        gll16(arow + (size_t)c * CHB + sub * 16, Ash + r * 15360 + ch * 1024);
      }
      for (int ch = wid; ch < 15; ch += 2) {
        int t16 = ch * 64 + lane;
        int c = t16 / 15, sub = t16 - c * 15;
        gll16(brow + (size_t)c * CHB + sub * 16, Bsh + r * 15360 + ch * 1024);
      }
    }
    __syncthreads();
    if (wid < rows) {
      const unsigned char* Ar = Ash + wid * 15360;
      const unsigned char* Br = Bsh + wid * 15360;
#pragma unroll
      for (int kt = 0; kt < 6; ++kt) {
        int off = 16 + kt * 32 + l5 * 16;   // f16 idx 8 + 16*kt + 8*(lane>>5)
        f16x8_t a0 = *(const f16x8_t*)(Ar + l31 * ROWB + off);
        f16x8_t a1 = *(const f16x8_t*)(Ar + (l31 + 32) * ROWB + off);
        f16x8_t b0 = *(const f16x8_t*)(Br + l31 * ROWB + off);
        f16x8_t b1 = *(const f16x8_t*)(Br + (l31 + 32) * ROWB + off);
        acc[0][0] = __builtin_amdgcn_mfma_f32_32x32x16_f16(a0, b0, acc[0][0], 0, 0, 0);
        acc[0][1] = __builtin_amdgcn_mfma_f32_32x32x16_f16(a0, b1, acc[0][1], 0, 0, 0);
        acc[1][0] = __builtin_amdgcn_mfma_f32_32x32x16_f16(a1, b0, acc[1][0], 0, 0, 0);
        acc[1][1] = __builtin_amdgcn_mfma_f32_32x32x16_f16(a1, b1, acc[1][1], 0, 0, 0);
      }
    }
  }

  // epilogue: cross-wave sum, write main + mirror slices
  __syncthreads();
  float* red = (float*)Ash;        // 64 x 65 f32 scratch
  if (wid == 0) {
#pragma unroll
    for (int mt = 0; mt < 2; ++mt)
#pragma unroll
      for (int nt = 0; nt < 2; ++nt)
#pragma unroll
        for (int rg = 0; rg < 16; ++rg) {
          int m  = mt * 32 + (rg & 3) + 8 * (rg >> 2) + 4 * l5;   // C/D row (m74/m101)
          int nn = nt * 32 + l31;                                  // C/D col
          red[m * 65 + nn] = acc[mt][nt][rg];
        }
  }
  __syncthreads();
  if (wid == 1) {
    int mir = !(du == 4 && dv == 4);
    int o1 = du * 9 + dv, o2 = (8 - du) * 9 + (8 - dv);
#pragma unroll
    for (int mt = 0; mt < 2; ++mt)
#pragma unroll
      for (int nt = 0; nt < 2; ++nt)
#pragma unroll
        for (int rg = 0; rg < 16; ++rg) {
          int m  = mt * 32 + (rg & 3) + 8 * (rg >> 2) + 4 * l5;
          int nn = nt * 32 + l31;
          float v = red[m * 65 + nn] + acc[mt][nt][rg];
          corrP[((size_t)(n * 64 + m) * 64 + nn) * CORR_RS + o1] = v;
          if (mir) corrP[((size_t)(n * 64 + nn) * 64 + m) * CORR_RS + o2] = v;
        }
  }
}

// ---------------- xty kernel (proven) ----------------
__global__ __launch_bounds__(256) void xty_kernel(const float* __restrict__ xs,
                                                  const float* __restrict__ ys,
                                                  const float* __restrict__ dd,
                                                  const float* __restrict__ alpha,
                                                  const float* __restrict__ reg,
                                                  float* __restrict__ P) {
  int bid = blockIdx.x;          // ((n*CIN)+c)*COUT + b
  int b = bid & 3;
  int c = (bid >> 2) & 63;
  int n = bid >> 8;
  __shared__ float xp[100 * 100];
  __shared__ float redbuf[4][25];
  const float* xg = xs + (size_t)(n * CIN + c) * HWSZ;
  const float* yg = ys + (size_t)(n * COUT + b) * HWSZ;
  int tid = threadIdx.x;
  for (int i = tid; i < 100 * 100; i += 256) xp[i] = 0.f;
  __syncthreads();
  for (int i = tid; i < HWSZ; i += 256) {
    int h = i / 96, w = i - h * 96;
    xp[(h + 2) * 100 + (w + 2)] = xg[i];
  }
  __syncthreads();

  float acc[25];
#pragma unroll
  for (int k = 0; k < 25; ++k) acc[k] = 0.f;
  int tx = tid & 31, ty = tid >> 5;
  int w0 = tx * 3;
  for (int h = ty; h < 96; h += 8) {
    float y0 = yg[h * 96 + w0];
    float y1 = yg[h * 96 + w0 + 1];
    float y2 = yg[h * 96 + w0 + 2];
#pragma unroll
    for (int u = 0; u < 5; ++u) {
      const float* rowp = &xp[(h + u) * 100 + w0];
      float rbuf[7];
#pragma unroll
      for (int j = 0; j < 7; ++j) rbuf[j] = rowp[j];
#pragma unroll
      for (int v = 0; v < 5; ++v) {
        acc[u * 5 + v] += y0 * rbuf[v] + y1 * rbuf[v + 1] + y2 * rbuf[v + 2];
      }
    }
  }
  int wave = tid >> 6, lane = tid & 63;
#pragma unroll
  for (int k = 0; k < 25; ++k) {
    float s = waveAllSum(acc[k]);
    if (lane == 0) redbuf[wave][k] = s;
  }
  __syncthreads();
  if (tid < 25) {
    float tot = redbuf[0][tid] + redbuf[1][tid] + redbuf[2][tid] + redbuf[3][tid];
    float a = alpha[n] * reg[0] * ((float)(HH * WW) / (float)(DS * DS * CIN));
    float dv = dd[((size_t)(n * COUT + b) * CIN + c) * 25 + tid];
    P[((size_t)(n * KD) + c * 25 + tid) * COUT + b] = tot + a * dv;
  }
}

// ---------------- fused CG iteration (lean: creg direct from 84-padded global) ----------------
static __device__ __forceinline__ void allreduce2_f4(float4& a, float4& b,
                                                     float4* redA, float4* redB, int tid) {
#pragma unroll
  for (int off = 1; off < 64; off <<= 1) {
    a.x += __shfl_xor(a.x, off); a.y += __shfl_xor(a.y, off);
    a.z += __shfl_xor(a.z, off); a.w += __shfl_xor(a.w, off);
    b.x += __shfl_xor(b.x, off); b.y += __shfl_xor(b.y, off);
    b.z += __shfl_xor(b.z, off); b.w += __shfl_xor(b.w, off);
  }
  int wid = tid >> 6;
  if ((tid & 63) == 0) { redA[wid] = a; redB[wid] = b; }
  __syncthreads();
  float4 sa = f4add(f4add(redA[0], redA[1]), f4add(redA[2], redA[3]));
  float4 sb = f4add(f4add(redB[0], redB[1]), f4add(redB[2], redB[3]));
  __syncthreads();
  a = sa; b = sb;
}

__global__ __launch_bounds__(256) void cg_iter_kernel(
    const float* __restrict__ corrP, const float* __restrict__ P,
    const float* __restrict__ Rin, float* __restrict__ Rout,
    const float* __restrict__ Win, float* __restrict__ Wout,
    const float* __restrict__ PFin, float* __restrict__ PFout,
    float* __restrict__ X,
    const float* __restrict__ ralpha, const float* __restrict__ rreg,
    int first) {
  __shared__ float4 pS[KD];
  __shared__ float4 redA[4], redB[4];
  __shared__ float redW[4][25][4];

  int b = blockIdx.x;
  int n = b >> 6, c1 = b & 63;
  int tid = threadIdx.x;

  const float4* Rin4 = (const float4*)Rin + (size_t)n * KD;
  const float4* Win4 = (const float4*)Win + (size_t)n * KD;
  const float4* PFin4 = (const float4*)PFin + (size_t)n * KD;
  const float4* P4 = (const float4*)P + (size_t)n * KD;
  float4* Rout4 = (float4*)Rout + (size_t)n * KD;
  float4* PFout4 = (float4*)PFout + (size_t)n * KD;
  float4* X4 = (float4*)X + (size_t)n * KD;

  const float4 zero4 = make_float4(0.f, 0.f, 0.f, 0.f);
  float4 rv[7], wv[7], pv[7];
#pragma unroll
  for (int t = 0; t < 7; ++t) {
    int idx = tid + 256 * t;
    bool ok = idx < KD;
    if (first) {
      rv[t] = ok ? P4[idx] : zero4;
      wv[t] = zero4; pv[t] = zero4;
    } else {
      rv[t] = ok ? Rin4[idx] : zero4;
      wv[t] = ok ? Win4[idx] : zero4;
      pv[t] = ok ? PFin4[idx] : zero4;
    }
  }
  float4 rho_prev = zero4, pAp = zero4;
#pragma unroll
  for (int t = 0; t < 7; ++t) {
    rho_prev = f4fma(rv[t], rv[t], rho_prev);
    pAp = f4fma(pv[t], wv[t], pAp);
  }
  allreduce2_f4(rho_prev, pAp, redA, redB, tid);

  float4 av = first ? zero4 : f4div(rho_prev, pAp);   // alpha_{k-1}

  float4 rho_k = zero4;
#pragma unroll
  for (int t = 0; t < 7; ++t) {
    rv[t] = f4sub(rv[t], f4mul(av, wv[t]));
    rho_k = f4fma(rv[t], rv[t], rho_k);
  }
  int lo = c1 * 25;
#pragma unroll
  for (int t = 0; t < 7; ++t) {
    int idx = tid + 256 * t;
    if (idx >= lo && idx < lo + 25) {
      if (first) X4[idx] = zero4;
      else X4[idx] = f4fma(av, pv[t], X4[idx]);
    }
  }
  float4 dummy = zero4;
  allreduce2_f4(rho_k, dummy, redA, redB, tid);

  float4 bv = first ? zero4 : f4div(rho_k, rho_prev);

#pragma unroll
  for (int t = 0; t < 7; ++t) {
    int idx = tid + 256 * t;
    if (idx < KD) {
      float4 pnew = f4fma(bv, pv[t], rv[t]);
      pS[idx] = pnew;
      if (idx >= lo && idx < lo + 25) {
        PFout4[idx] = pnew;
        Rout4[idx] = rv[t];
      }
    }
  }
  __syncthreads();

  int c2 = tid >> 2, col = tid & 3;
  const float4* crow4 = (const float4*)(corrP + (((size_t)(n * 64 + c1)) * 64 + c2) * CORR_RS);
  float creg[81];
#pragma unroll
  for (int t4 = 0; t4 < 20; ++t4) *(float4*)&creg[4 * t4] = crow4[t4];
  creg[80] = ((const float*)crow4)[80];

  float a25[25];
#pragma unroll
  for (int i = 0; i < 25; ++i) a25[i] = 0.f;
  const float* pSf = (const float*)pS;
#pragma unroll
  for (int j = 0; j < 25; ++j) {
    float pvv = pSf[(c2 * 25 + j) * 4 + col];
#pragma unroll
    for (int i = 0; i < 25; ++i) {
      const int i1 = i / 5, i2 = i % 5, j1 = j / 5, j2 = j % 5;
      a25[i] += creg[(j1 - i1 + 4) * 9 + (j2 - i2 + 4)] * pvv;
    }
  }
#pragma unroll
  for (int i = 0; i < 25; ++i) {
    float v = a25[i];
    v += __shfl_xor(v, 4); v += __shfl_xor(v, 8);
    v += __shfl_xor(v, 16); v += __shfl_xor(v, 32);
    a25[i] = v;
  }
  int wid = tid >> 6;
  if ((tid & 63) < 4) {
#pragma unroll
    for (int i = 0; i < 25; ++i) redW[wid][i][col] = a25[i];
  }
  __syncthreads();
  if (tid < 100) {
    int i = tid >> 2, cc = tid & 3;
    float wval = redW[0][i][cc] + redW[1][i][cc] + redW[2][i][cc] + redW[3][i][cc];
    float aa = ralpha[n] * rreg[0] * ((float)(HH * WW) / (float)(DS * DS * CIN));
    int row = lo + i;
    wval = fmaf(aa, pSf[row * 4 + cc], wval);
    Wout[((size_t)n * KD + row) * 4 + cc] = wval;
  }
}

// ---------------- finalize ----------------
__global__ __launch_bounds__(256) void cg_final_kernel(
    const float* __restrict__ Rin, const float* __restrict__ Win,
    const float* __restrict__ PFin, const float* __restrict__ X,
    float* __restrict__ out) {
  __shared__ float4 redA[4], redB[4];
  int b = blockIdx.x;
  int n = b >> 6, c1 = b & 63;
  int tid = threadIdx.x;

  const float4* Rin4 = (const float4*)Rin + (size_t)n * KD;
  const float4* Win4 = (const float4*)Win + (size_t)n * KD;
  const float4* PFin4 = (const float4*)PFin + (size_t)n * KD;
  const float4 zero4 = make_float4(0.f, 0.f, 0.f, 0.f);

  float4 rho = zero4, pAp = zero4;
#pragma unroll
  for (int t = 0; t < 7; ++t) {
    int idx = tid + 256 * t;
    if (idx < KD) {
      float4 r = Rin4[idx], w = Win4[idx], p = PFin4[idx];
      rho = f4fma(r, r, rho);
      pAp = f4fma(p, w, pAp);
    }
  }
  allreduce2_f4(rho, pAp, redA, redB, tid);
  float4 av = f4div(rho, pAp);

  if (tid < 100) {
    int i = tid >> 2, cc = tid & 3;
    int row = c1 * 25 + i;
    float a_cc = f4sel(av, cc);
    float xv = X[((size_t)n * KD + row) * 4 + cc] + a_cc * PFin[((size_t)n * KD + row) * 4 + cc];
    out[((size_t)(n * 4 + cc) * 64 + c1) * 25 + i] = xv;
  }
}

extern "C" void kernel_launch(void* const* d_in, const int* in_sizes, int n_in,
                              void* d_out, int out_size, void* d_ws, size_t ws_size,
                              hipStream_t stream) {
  (void)in_sizes; (void)n_in; (void)out_size; (void)ws_size;
  const float* xs    = (const float*)d_in[0];   // [4,1,64,96,96]
  const float* dd    = (const float*)d_in[1];   // [4,4,64,5,5]
  const float* ys    = (const float*)d_in[2];   // [4,4,1,96,96]
  const float* alpha = (const float*)d_in[3];   // [4]
  const float* reg   = (const float*)d_in[4];   // [1]
  float* out = (float*)d_out;
  float* ws  = (float*)d_ws;

  const size_t XELEM = (size_t)256 * 96 * ROWF;          // f16 per shift buffer
  const size_t SZ_CORR = (size_t)NS * 64 * 64 * CORR_RS; // 1,376,256 floats
  const size_t SZ_V = (size_t)NS * KD * COUT;            // 25,600 floats

  unsigned short* XS = (unsigned short*)ws;              // 5 shift buffers
  float* corrP = (float*)(XS + 5 * XELEM);               // 16B-aligned (29,491,200 % 16 == 0)
  float* P   = corrP + SZ_CORR;
  float* X   = P + SZ_V;
  float* R0  = X + SZ_V;
  float* R1  = R0 + SZ_V;
  float* W0  = R1 + SZ_V;
  float* W1  = W0 + SZ_V;
  float* PF0 = W1 + SZ_V;
  float* PF1 = PF0 + SZ_V;
  float* Rb[2] = {R0, R1};
  float* Wb[2] = {W0, W1};
  float* Pb[2] = {PF0, PF1};

  convert_kernel<<<28800, 256, 0, stream>>>(xs, (unsigned int*)XS);
  corr_mfma_kernel<<<NS * 41, 128, 0, stream>>>(XS, corrP);
  xty_kernel<<<NS * CIN * COUT, 256, 0, stream>>>(xs, ys, dd, alpha, reg, P);
  for (int k = 0; k < ITER; ++k) {
    cg_iter_kernel<<<NS * CIN, 256, 0, stream>>>(
        corrP, P,
        Rb[k & 1], Rb[(k + 1) & 1],
        Wb[k & 1], Wb[(k + 1) & 1],
        Pb[k & 1], Pb[(k + 1) & 1],
        X, alpha, reg, k == 0 ? 1 : 0);
  }
  cg_final_kernel<<<NS * CIN, 256, 0, stream>>>(Rb[ITER & 1], Wb[ITER & 1], Pb[ITER & 1], X, out);
}

// Round 8
// 186.012 us; speedup vs baseline: 14.0993x; 1.4524x over previous
//
#include <hip/hip_runtime.h>

// Problem constants
#define NS   4
#define CIN  64
#define COUT 4
#define HH   96
#define WW   96
#define HWSZ 9216
#define DS   5
#define KD   1600
#define ITER 9

// Padded f16 image geometry
#define ROWF 120                    // f16 per padded row
#define ROWB 240                    // bytes per padded row (15 x 16B chunks)
#define CHB  (96*ROWB)              // channel stride bytes (23040)
#define IMGB ((size_t)64*CHB)       // per-sample bytes
#define XSB  ((size_t)256*CHB)      // per-shift-buffer bytes
#define CORR_RS 84                  // corr row stride in floats

#define SK   8                      // split-K row chunks
#define RPC  12                     // rows per chunk

typedef _Float16 f16_t;
typedef _Float16 f16x8_t __attribute__((ext_vector_type(8)));
typedef float    f32x16_t __attribute__((ext_vector_type(16)));

static __device__ __forceinline__ void gll16(const void* g, void* l) {
  __builtin_amdgcn_global_load_lds((const __attribute__((address_space(1))) unsigned int*)g,
                                   (__attribute__((address_space(3))) unsigned int*)l, 16, 0, 0);
}

static __device__ __forceinline__ float waveAllSum(float v) {
#pragma unroll
  for (int off = 32; off; off >>= 1) v += __shfl_xor(v, off);
  return v;
}
static __device__ __forceinline__ float4 f4add(float4 a, float4 b) {
  return make_float4(a.x + b.x, a.y + b.y, a.z + b.z, a.w + b.w);
}
static __device__ __forceinline__ float4 f4sub(float4 a, float4 b) {
  return make_float4(a.x - b.x, a.y - b.y, a.z - b.z, a.w - b.w);
}
static __device__ __forceinline__ float4 f4mul(float4 a, float4 b) {
  return make_float4(a.x * b.x, a.y * b.y, a.z * b.z, a.w * b.w);
}
static __device__ __forceinline__ float4 f4div(float4 a, float4 b) {
  return make_float4(a.x / b.x, a.y / b.y, a.z / b.z, a.w / b.w);
}
static __device__ __forceinline__ float4 f4fma(float4 a, float4 b, float4 c) {
  return make_float4(fmaf(a.x, b.x, c.x), fmaf(a.y, b.y, c.y),
                     fmaf(a.z, b.z, c.z), fmaf(a.w, b.w, c.w));
}
static __device__ __forceinline__ float f4sel(float4 v, int c) {
  return c == 0 ? v.x : c == 1 ? v.y : c == 2 ? v.z : v.w;
}

// ---------------- convert: xs fp32 -> 5 shifted padded f16 images ----------------
__global__ __launch_bounds__(256) void convert_kernel(const float* __restrict__ xs,
                                                      unsigned int* __restrict__ XS32) {
  const int PERBUF = 256 * 96 * 60;
  int idx = blockIdx.x * 256 + threadIdx.x;
  if (idx >= 5 * PERBUF) return;
  int s = idx / PERBUF;
  int rr = idx - s * PERBUF;
  int p = rr % 60; int t = rr / 60;
  int r = t % 96;  int c = t / 96;
  const float* row = xs + (size_t)c * HWSZ + r * 96;
  int lo = 8 - s;
  int i0 = 2 * p, i1 = i0 + 1;
  float f0 = (i0 >= lo && i0 < lo + 96) ? row[i0 - lo] : 0.f;
  float f1 = (i1 >= lo && i1 < lo + 96) ? row[i1 - lo] : 0.f;
  f16_t h0 = (f16_t)f0, h1 = (f16_t)f1;
  unsigned int pk = (unsigned int)__builtin_bit_cast(unsigned short, h0)
                  | ((unsigned int)__builtin_bit_cast(unsigned short, h1) << 16);
  XS32[(size_t)s * PERBUF + (size_t)c * (96 * 60) + r * 60 + p] = pk;
}

// ---------------- corr partial: split-K MFMA ----------------
// bid = g + 32*p; g = kc*4 + n (same-(n,kc) groups share an XCD under %8 round-robin).
// Block computes 64x64 partial C over its <=12 rows; wave q owns quadrant (mt,nt).
// Per row: stage A row (XS_0) + B row (XS_{dv-4}) via global_load_lds 16B, double
// buffered (issue next stage -> consume 12 ds_read_b128 + 6 MFMA -> barrier).
__global__ __launch_bounds__(256, 2) void corr_partial_kernel(const unsigned short* __restrict__ XS,
                                                              float* __restrict__ corrPart) {
  __shared__ __align__(16) unsigned char sh[2][2][15360];   // [buf][A/B][64ch x 240B]
  int bid = blockIdx.x;
  int g = bid & 31, p = bid >> 5;
  int n = g & 3, kc = g >> 2;
  int du, dv;
  if (p < 36) { du = p % 9; dv = 5 + p / 9; }
  else        { du = p - 36; dv = 4; }
  const char* An = (const char*)XS + (size_t)n * IMGB;
  const char* Bn = (const char*)XS + (size_t)(dv - 4) * XSB + (size_t)n * IMGB;
  int h0 = (du < 4) ? (4 - du) : 0;
  int nR = (du < 4) ? (92 + du) : (100 - du);
  int r0 = kc * RPC;
  int nrows = nR - r0; if (nrows > RPC) nrows = RPC;   // in [8,12]
  int tid = threadIdx.x, wid = tid >> 6, lane = tid & 63;
  int l5 = lane >> 5, l31 = lane & 31;
  int mt = wid >> 1, nt = wid & 1;
  f32x16_t acc = {};

  auto stage = [&](int buf, int rI) {
    int hA = h0 + rI, hB = hA + du - 4;
    const char* arow = An + (size_t)hA * ROWB;
    const char* brow = Bn + (size_t)hB * ROWB;
#pragma unroll
    for (int k = 0; k < 4; ++k) {
      int i = k * 256 + tid;
      if (i < 960) {                       // wave-uniform predicate (wave 3 @ k=3 masked)
        int c = i / 15, sub = i - c * 15;
        char* la = (char*)&sh[buf][0][0] + (size_t)(k * 256 + wid * 64) * 16;
        char* lb = (char*)&sh[buf][1][0] + (size_t)(k * 256 + wid * 64) * 16;
        gll16(arow + (size_t)c * CHB + sub * 16, la);
        gll16(brow + (size_t)c * CHB + sub * 16, lb);
      }
    }
  };

  stage(0, r0 - r0);                       // rI is relative: use absolute helper below
  // NOTE: stage takes relative rI? pass absolute row index instead:
  // (we re-call with absolute indices; first call staged rI=0 => row r0? No.)
  // -- To keep it unambiguous, restage properly:
  __syncthreads();
  // The call above staged hA = h0 + 0; we want h0 + r0. Redo staging loop cleanly:
  // (cheap: correctness over cleverness — re-issue correct row 0 of this chunk)
  stage(0, r0);
  __syncthreads();

  int buf = 0;
  for (int r = 0; r < nrows; ++r) {
    if (r + 1 < nrows) stage(buf ^ 1, r0 + r + 1);
    const unsigned char* Ar = &sh[buf][0][0];
    const unsigned char* Br = &sh[buf][1][0];
#pragma unroll
    for (int kt = 0; kt < 6; ++kt) {
      int off = 16 + kt * 32 + l5 * 16;
      f16x8_t a = *(const f16x8_t*)(Ar + (size_t)(mt * 32 + l31) * ROWB + off);
      f16x8_t b = *(const f16x8_t*)(Br + (size_t)(nt * 32 + l31) * ROWB + off);
      acc = __builtin_amdgcn_mfma_f32_32x32x16_f16(a, b, acc, 0, 0, 0);
    }
    __syncthreads();
    buf ^= 1;
  }

  float* outp = corrPart + ((size_t)p * 32 + g) * 4096;
#pragma unroll
  for (int rg = 0; rg < 16; ++rg) {
    int m  = mt * 32 + (rg & 3) + 8 * (rg >> 2) + 4 * l5;
    int nn = nt * 32 + l31;
    outp[m * 64 + nn] = acc[rg];
  }
}

// ---------------- corr reduce: sum 8 chunk partials, write main + mirror ----------------
__global__ __launch_bounds__(256) void corr_reduce_kernel(const float* __restrict__ corrPart,
                                                          float* __restrict__ corrP) {
  int bid = blockIdx.x;              // n*41 + p
  int n = bid / 41, p = bid % 41;
  int du, dv;
  if (p < 36) { du = p % 9; dv = 5 + p / 9; }
  else        { du = p - 36; dv = 4; }
  int o1 = du * 9 + dv, o2 = (8 - du) * 9 + (8 - dv);
  bool mir = !(du == 4 && dv == 4);
  for (int e = threadIdx.x; e < 4096; e += 256) {
    float s = 0.f;
#pragma unroll
    for (int kc = 0; kc < 8; ++kc)
      s += corrPart[((size_t)p * 32 + kc * 4 + n) * 4096 + e];
    int m = e >> 6, nn = e & 63;
    corrP[((size_t)(n * 64 + m) * 64 + nn) * CORR_RS + o1] = s;
    if (mir) corrP[((size_t)(n * 64 + nn) * 64 + m) * CORR_RS + o2] = s;
  }
}

// ---------------- xty kernel (proven) ----------------
__global__ __launch_bounds__(256) void xty_kernel(const float* __restrict__ xs,
                                                  const float* __restrict__ ys,
                                                  const float* __restrict__ dd,
                                                  const float* __restrict__ alpha,
                                                  const float* __restrict__ reg,
                                                  float* __restrict__ P) {
  int bid = blockIdx.x;          // ((n*CIN)+c)*COUT + b
  int b = bid & 3;
  int c = (bid >> 2) & 63;
  int n = bid >> 8;
  __shared__ float xp[100 * 100];
  __shared__ float redbuf[4][25];
  const float* xg = xs + (size_t)(n * CIN + c) * HWSZ;
  const float* yg = ys + (size_t)(n * COUT + b) * HWSZ;
  int tid = threadIdx.x;
  for (int i = tid; i < 100 * 100; i += 256) xp[i] = 0.f;
  __syncthreads();
  for (int i = tid; i < HWSZ; i += 256) {
    int h = i / 96, w = i - h * 96;
    xp[(h + 2) * 100 + (w + 2)] = xg[i];
  }
  __syncthreads();

  float acc[25];
#pragma unroll
  for (int k = 0; k < 25; ++k) acc[k] = 0.f;
  int tx = tid & 31, ty = tid >> 5;
  int w0 = tx * 3;
  for (int h = ty; h < 96; h += 8) {
    float y0 = yg[h * 96 + w0];
    float y1 = yg[h * 96 + w0 + 1];
    float y2 = yg[h * 96 + w0 + 2];
#pragma unroll
    for (int u = 0; u < 5; ++u) {
      const float* rowp = &xp[(h + u) * 100 + w0];
      float rbuf[7];
#pragma unroll
      for (int j = 0; j < 7; ++j) rbuf[j] = rowp[j];
#pragma unroll
      for (int v = 0; v < 5; ++v) {
        acc[u * 5 + v] += y0 * rbuf[v] + y1 * rbuf[v + 1] + y2 * rbuf[v + 2];
      }
    }
  }
  int wave = tid >> 6, lane = tid & 63;
#pragma unroll
  for (int k = 0; k < 25; ++k) {
    float s = waveAllSum(acc[k]);
    if (lane == 0) redbuf[wave][k] = s;
  }
  __syncthreads();
  if (tid < 25) {
    float tot = redbuf[0][tid] + redbuf[1][tid] + redbuf[2][tid] + redbuf[3][tid];
    float a = alpha[n] * reg[0] * ((float)(HH * WW) / (float)(DS * DS * CIN));
    float dvv = dd[((size_t)(n * COUT + b) * CIN + c) * 25 + tid];
    P[((size_t)(n * KD) + c * 25 + tid) * COUT + b] = tot + a * dvv;
  }
}

// ---------------- fused CG iteration (proven) ----------------
static __device__ __forceinline__ void allreduce2_f4(float4& a, float4& b,
                                                     float4* redA, float4* redB, int tid) {
#pragma unroll
  for (int off = 1; off < 64; off <<= 1) {
    a.x += __shfl_xor(a.x, off); a.y += __shfl_xor(a.y, off);
    a.z += __shfl_xor(a.z, off); a.w += __shfl_xor(a.w, off);
    b.x += __shfl_xor(b.x, off); b.y += __shfl_xor(b.y, off);
    b.z += __shfl_xor(b.z, off); b.w += __shfl_xor(b.w, off);
  }
  int wid = tid >> 6;
  if ((tid & 63) == 0) { redA[wid] = a; redB[wid] = b; }
  __syncthreads();
  float4 sa = f4add(f4add(redA[0], redA[1]), f4add(redA[2], redA[3]));
  float4 sb = f4add(f4add(redB[0], redB[1]), f4add(redB[2], redB[3]));
  __syncthreads();
  a = sa; b = sb;
}

__global__ __launch_bounds__(256) void cg_iter_kernel(
    const float* __restrict__ corrP, const float* __restrict__ P,
    const float* __restrict__ Rin, float* __restrict__ Rout,
    const float* __restrict__ Win, float* __restrict__ Wout,
    const float* __restrict__ PFin, float* __restrict__ PFout,
    float* __restrict__ X,
    const float* __restrict__ ralpha, const float* __restrict__ rreg,
    int first) {
  __shared__ float4 pS[KD];
  __shared__ float4 redA[4], redB[4];
  __shared__ float redW[4][25][4];

  int b = blockIdx.x;
  int n = b >> 6, c1 = b & 63;
  int tid = threadIdx.x;

  const float4* Rin4 = (const float4*)Rin + (size_t)n * KD;
  const float4* Win4 = (const float4*)Win + (size_t)n * KD;
  const float4* PFin4 = (const float4*)PFin + (size_t)n * KD;
  const float4* P4 = (const float4*)P + (size_t)n * KD;
  float4* Rout4 = (float4*)Rout + (size_t)n * KD;
  float4* PFout4 = (float4*)PFout + (size_t)n * KD;
  float4* X4 = (float4*)X + (size_t)n * KD;

  const float4 zero4 = make_float4(0.f, 0.f, 0.f, 0.f);
  float4 rv[7], wv[7], pv[7];
#pragma unroll
  for (int t = 0; t < 7; ++t) {
    int idx = tid + 256 * t;
    bool ok = idx < KD;
    if (first) {
      rv[t] = ok ? P4[idx] : zero4;
      wv[t] = zero4; pv[t] = zero4;
    } else {
      rv[t] = ok ? Rin4[idx] : zero4;
      wv[t] = ok ? Win4[idx] : zero4;
      pv[t] = ok ? PFin4[idx] : zero4;
    }
  }
  float4 rho_prev = zero4, pAp = zero4;
#pragma unroll
  for (int t = 0; t < 7; ++t) {
    rho_prev = f4fma(rv[t], rv[t], rho_prev);
    pAp = f4fma(pv[t], wv[t], pAp);
  }
  allreduce2_f4(rho_prev, pAp, redA, redB, tid);

  float4 av = first ? zero4 : f4div(rho_prev, pAp);

  float4 rho_k = zero4;
#pragma unroll
  for (int t = 0; t < 7; ++t) {
    rv[t] = f4sub(rv[t], f4mul(av, wv[t]));
    rho_k = f4fma(rv[t], rv[t], rho_k);
  }
  int lo = c1 * 25;
#pragma unroll
  for (int t = 0; t < 7; ++t) {
    int idx = tid + 256 * t;
    if (idx >= lo && idx < lo + 25) {
      if (first) X4[idx] = zero4;
      else X4[idx] = f4fma(av, pv[t], X4[idx]);
    }
  }
  float4 dummy = zero4;
  allreduce2_f4(rho_k, dummy, redA, redB, tid);

  float4 bv = first ? zero4 : f4div(rho_k, rho_prev);

#pragma unroll
  for (int t = 0; t < 7; ++t) {
    int idx = tid + 256 * t;
    if (idx < KD) {
      float4 pnew = f4fma(bv, pv[t], rv[t]);
      pS[idx] = pnew;
      if (idx >= lo && idx < lo + 25) {
        PFout4[idx] = pnew;
        Rout4[idx] = rv[t];
      }
    }
  }
  __syncthreads();

  int c2 = tid >> 2, col = tid & 3;
  const float4* crow4 = (const float4*)(corrP + (((size_t)(n * 64 + c1)) * 64 + c2) * CORR_RS);
  float creg[81];
#pragma unroll
  for (int t4 = 0; t4 < 20; ++t4) *(float4*)&creg[4 * t4] = crow4[t4];
  creg[80] = ((const float*)crow4)[80];

  float a25[25];
#pragma unroll
  for (int i = 0; i < 25; ++i) a25[i] = 0.f;
  const float* pSf = (const float*)pS;
#pragma unroll
  for (int j = 0; j < 25; ++j) {
    float pvv = pSf[(c2 * 25 + j) * 4 + col];
#pragma unroll
    for (int i = 0; i < 25; ++i) {
      const int i1 = i / 5, i2 = i % 5, j1 = j / 5, j2 = j % 5;
      a25[i] += creg[(j1 - i1 + 4) * 9 + (j2 - i2 + 4)] * pvv;
    }
  }
#pragma unroll
  for (int i = 0; i < 25; ++i) {
    float v = a25[i];
    v += __shfl_xor(v, 4); v += __shfl_xor(v, 8);
    v += __shfl_xor(v, 16); v += __shfl_xor(v, 32);
    a25[i] = v;
  }
  int wid = tid >> 6;
  if ((tid & 63) < 4) {
#pragma unroll
    for (int i = 0; i < 25; ++i) redW[wid][i][col] = a25[i];
  }
  __syncthreads();
  if (tid < 100) {
    int i = tid >> 2, cc = tid & 3;
    float wval = redW[0][i][cc] + redW[1][i][cc] + redW[2][i][cc] + redW[3][i][cc];
    float aa = ralpha[n] * rreg[0] * ((float)(HH * WW) / (float)(DS * DS * CIN));
    int row = lo + i;
    wval = fmaf(aa, pSf[row * 4 + cc], wval);
    Wout[((size_t)n * KD + row) * 4 + cc] = wval;
  }
}

// ---------------- finalize ----------------
__global__ __launch_bounds__(256) void cg_final_kernel(
    const float* __restrict__ Rin, const float* __restrict__ Win,
    const float* __restrict__ PFin, const float* __restrict__ X,
    float* __restrict__ out) {
  __shared__ float4 redA[4], redB[4];
  int b = blockIdx.x;
  int n = b >> 6, c1 = b & 63;
  int tid = threadIdx.x;

  const float4* Rin4 = (const float4*)Rin + (size_t)n * KD;
  const float4* Win4 = (const float4*)Win + (size_t)n * KD;
  const float4* PFin4 = (const float4*)PFin + (size_t)n * KD;
  const float4 zero4 = make_float4(0.f, 0.f, 0.f, 0.f);

  float4 rho = zero4, pAp = zero4;
#pragma unroll
  for (int t = 0; t < 7; ++t) {
    int idx = tid + 256 * t;
    if (idx < KD) {
      float4 r = Rin4[idx], w = Win4[idx], p = PFin4[idx];
      rho = f4fma(r, r, rho);
      pAp = f4fma(p, w, pAp);
    }
  }
  allreduce2_f4(rho, pAp, redA, redB, tid);
  float4 av = f4div(rho, pAp);

  if (tid < 100) {
    int i = tid >> 2, cc = tid & 3;
    int row = c1 * 25 + i;
    float a_cc = f4sel(av, cc);
    float xv = X[((size_t)n * KD + row) * 4 + cc] + a_cc * PFin[((size_t)n * KD + row) * 4 + cc];
    out[((size_t)(n * 4 + cc) * 64 + c1) * 25 + i] = xv;
  }
}

extern "C" void kernel_launch(void* const* d_in, const int* in_sizes, int n_in,
                              void* d_out, int out_size, void* d_ws, size_t ws_size,
                              hipStream_t stream) {
  (void)in_sizes; (void)n_in; (void)out_size; (void)ws_size;
  const float* xs    = (const float*)d_in[0];   // [4,1,64,96,96]
  const float* dd    = (const float*)d_in[1];   // [4,4,64,5,5]
  const float* ys    = (const float*)d_in[2];   // [4,4,1,96,96]
  const float* alpha = (const float*)d_in[3];   // [4]
  const float* reg   = (const float*)d_in[4];   // [1]
  float* out = (float*)d_out;
  float* ws  = (float*)d_ws;

  const size_t XELEM = (size_t)256 * 96 * ROWF;           // f16 per shift buffer
  const size_t XS_FLOATS = 5 * XELEM / 2;                 // 7,372,800 floats
  const size_t SZ_PART = (size_t)41 * 32 * 4096;          // 5,373,952 floats
  const size_t SZ_V = (size_t)NS * KD * COUT;             // 25,600 floats

  unsigned short* XS = (unsigned short*)ws;               // 29.5 MB (dead after corr_partial)
  float* corrP = ws;                                      // 5.5 MB, overlays dead XS
  float* corrPart = ws + XS_FLOATS;                       // 21.5 MB
  float* P   = corrPart + SZ_PART;
  float* X   = P + SZ_V;
  float* R0  = X + SZ_V;
  float* R1  = R0 + SZ_V;
  float* W0  = R1 + SZ_V;
  float* W1  = W0 + SZ_V;
  float* PF0 = W1 + SZ_V;
  float* PF1 = PF0 + SZ_V;
  float* Rb[2] = {R0, R1};
  float* Wb[2] = {W0, W1};
  float* Pb[2] = {PF0, PF1};

  convert_kernel<<<28800, 256, 0, stream>>>(xs, (unsigned int*)XS);
  corr_partial_kernel<<<41 * 32, 256, 0, stream>>>(XS, corrPart);
  corr_reduce_kernel<<<NS * 41, 256, 0, stream>>>(corrPart, corrP);
  xty_kernel<<<NS * CIN * COUT, 256, 0, stream>>>(xs, ys, dd, alpha, reg, P);
  for (int k = 0; k < ITER; ++k) {
    cg_iter_kernel<<<NS * CIN, 256, 0, stream>>>(
        corrP, P,
        Rb[k & 1], Rb[(k + 1) & 1],
        Wb[k & 1], Wb[(k + 1) & 1],
        Pb[k & 1], Pb[(k + 1) & 1],
        X, alpha, reg, k == 0 ? 1 : 0);
  }
  cg_final_kernel<<<NS * CIN, 256, 0, stream>>>(Rb[ITER & 1], Wb[ITER & 1], Pb[ITER & 1], X, out);
}

// Round 9
// 165.455 us; speedup vs baseline: 15.8511x; 1.1242x over previous
//
#include <hip/hip_runtime.h>

// Problem constants
#define NS   4
#define CIN  64
#define COUT 4
#define HH   96
#define WW   96
#define HWSZ 9216
#define DS   5
#define KD   1600
#define ITER 7

// Padded f16 image geometry
#define ROWF 120                    // f16 per padded row
#define ROWB 240                    // bytes per padded row (15 x 16B chunks)
#define CHB  (96*ROWB)              // channel stride bytes (23040)
#define IMGB ((size_t)64*CHB)       // per-sample bytes
#define XSB  ((size_t)256*CHB)      // per-shift-buffer bytes
#define CORR_RS 84                  // corr row stride in floats

#define SK   4                      // split-K row chunks
#define RPC  25                     // rows per chunk (nR <= 100)

typedef _Float16 f16_t;
typedef _Float16 f16x8_t __attribute__((ext_vector_type(8)));
typedef float    f32x16_t __attribute__((ext_vector_type(16)));

static __device__ __forceinline__ void gll16(const void* g, void* l) {
  __builtin_amdgcn_global_load_lds((const __attribute__((address_space(1))) unsigned int*)g,
                                   (__attribute__((address_space(3))) unsigned int*)l, 16, 0, 0);
}

static __device__ __forceinline__ float waveAllSum(float v) {
#pragma unroll
  for (int off = 32; off; off >>= 1) v += __shfl_xor(v, off);
  return v;
}
static __device__ __forceinline__ float4 f4add(float4 a, float4 b) {
  return make_float4(a.x + b.x, a.y + b.y, a.z + b.z, a.w + b.w);
}
static __device__ __forceinline__ float4 f4sub(float4 a, float4 b) {
  return make_float4(a.x - b.x, a.y - b.y, a.z - b.z, a.w - b.w);
}
static __device__ __forceinline__ float4 f4mul(float4 a, float4 b) {
  return make_float4(a.x * b.x, a.y * b.y, a.z * b.z, a.w * b.w);
}
static __device__ __forceinline__ float4 f4div(float4 a, float4 b) {
  return make_float4(a.x / b.x, a.y / b.y, a.z / b.z, a.w / b.w);
}
static __device__ __forceinline__ float4 f4fma(float4 a, float4 b, float4 c) {
  return make_float4(fmaf(a.x, b.x, c.x), fmaf(a.y, b.y, c.y),
                     fmaf(a.z, b.z, c.z), fmaf(a.w, b.w, c.w));
}
static __device__ __forceinline__ float f4sel(float4 v, int c) {
  return c == 0 ? v.x : c == 1 ? v.y : c == 2 ? v.z : v.w;
}

// ---------------- convert: xs fp32 -> 5 shifted padded f16 images ----------------
__global__ __launch_bounds__(256) void convert_kernel(const float* __restrict__ xs,
                                                      unsigned int* __restrict__ XS32) {
  const int PERBUF = 256 * 96 * 60;
  int idx = blockIdx.x * 256 + threadIdx.x;
  if (idx >= 5 * PERBUF) return;
  int s = idx / PERBUF;
  int rr = idx - s * PERBUF;
  int p = rr % 60; int t = rr / 60;
  int r = t % 96;  int c = t / 96;
  const float* row = xs + (size_t)c * HWSZ + r * 96;
  int lo = 8 - s;
  int i0 = 2 * p, i1 = i0 + 1;
  float f0 = (i0 >= lo && i0 < lo + 96) ? row[i0 - lo] : 0.f;
  float f1 = (i1 >= lo && i1 < lo + 96) ? row[i1 - lo] : 0.f;
  f16_t h0 = (f16_t)f0, h1 = (f16_t)f1;
  unsigned int pk = (unsigned int)__builtin_bit_cast(unsigned short, h0)
                  | ((unsigned int)__builtin_bit_cast(unsigned short, h1) << 16);
  XS32[(size_t)s * PERBUF + (size_t)c * (96 * 60) + r * 60 + p] = pk;
}

// ---------------- corr partial: split-K MFMA ----------------
// bid = g + 16*p; g = kc*4 + n. Block computes 64x64 partial C over <=25 rows;
// wave q owns quadrant (mt,nt). Per row: stage A row (XS_0) + B row (XS_{dv-4})
// via global_load_lds 16B, double buffered.
__global__ __launch_bounds__(256, 2) void corr_partial_kernel(const unsigned short* __restrict__ XS,
                                                              float* __restrict__ corrPart) {
  __shared__ __align__(16) unsigned char sh[2][2][15360];   // [buf][A/B][64ch x 240B]
  int bid = blockIdx.x;
  int g = bid & 15, p = bid >> 4;
  int n = g & 3, kc = g >> 2;
  int du, dv;
  if (p < 36) { du = p % 9; dv = 5 + p / 9; }
  else        { du = p - 36; dv = 4; }
  const char* An = (const char*)XS + (size_t)n * IMGB;
  const char* Bn = (const char*)XS + (size_t)(dv - 4) * XSB + (size_t)n * IMGB;
  int h0 = (du < 4) ? (4 - du) : 0;
  int nR = (du < 4) ? (92 + du) : (100 - du);
  int r0 = kc * RPC;
  int nrows = nR - r0; if (nrows > RPC) nrows = RPC;   // in [17,25]
  int tid = threadIdx.x, wid = tid >> 6, lane = tid & 63;
  int l5 = lane >> 5, l31 = lane & 31;
  int mt = wid >> 1, nt = wid & 1;
  f32x16_t acc = {};

  auto stage = [&](int buf, int hA) {                  // hA = absolute padded A-row
    int hB = hA + du - 4;
    const char* arow = An + (size_t)hA * ROWB;
    const char* brow = Bn + (size_t)hB * ROWB;
#pragma unroll
    for (int k = 0; k < 4; ++k) {
      int i = k * 256 + tid;
      if (i < 960) {                                   // wave-uniform mask at k=3
        int c = i / 15, sub = i - c * 15;
        char* la = (char*)&sh[buf][0][0] + (size_t)(k * 256 + wid * 64) * 16;
        char* lb = (char*)&sh[buf][1][0] + (size_t)(k * 256 + wid * 64) * 16;
        gll16(arow + (size_t)c * CHB + sub * 16, la);
        gll16(brow + (size_t)c * CHB + sub * 16, lb);
      }
    }
  };

  stage(0, h0 + r0);
  __syncthreads();

  int buf = 0;
  for (int r = 0; r < nrows; ++r) {
    if (r + 1 < nrows) stage(buf ^ 1, h0 + r0 + r + 1);
    const unsigned char* Ar = &sh[buf][0][0];
    const unsigned char* Br = &sh[buf][1][0];
#pragma unroll
    for (int kt = 0; kt < 6; ++kt) {
      int off = 16 + kt * 32 + l5 * 16;
      f16x8_t a = *(const f16x8_t*)(Ar + (size_t)(mt * 32 + l31) * ROWB + off);
      f16x8_t b = *(const f16x8_t*)(Br + (size_t)(nt * 32 + l31) * ROWB + off);
      acc = __builtin_amdgcn_mfma_f32_32x32x16_f16(a, b, acc, 0, 0, 0);
    }
    __syncthreads();
    buf ^= 1;
  }

  float* outp = corrPart + ((size_t)p * 16 + g) * 4096;
#pragma unroll
  for (int rg = 0; rg < 16; ++rg) {
    int m  = mt * 32 + (rg & 3) + 8 * (rg >> 2) + 4 * l5;
    int nn = nt * 32 + l31;
    outp[m * 64 + nn] = acc[rg];
  }
}

// ---------------- fused: corr reduce (blocks 0..163) + xty (blocks 164..1187) ----------------
__global__ __launch_bounds__(256) void reduce_xty_kernel(const float* __restrict__ corrPart,
                                                         float* __restrict__ corrP,
                                                         const float* __restrict__ xs,
                                                         const float* __restrict__ ys,
                                                         const float* __restrict__ dd,
                                                         const float* __restrict__ alpha,
                                                         const float* __restrict__ reg,
                                                         float* __restrict__ P) {
  __shared__ float xp[100 * 100];
  __shared__ float redbuf[4][25];
  int bid0 = blockIdx.x;
  if (bid0 < 164) {
    // ---- corr reduce: sum 4 chunk partials, write main + mirror ----
    int n = bid0 / 41, p = bid0 % 41;
    int du, dv;
    if (p < 36) { du = p % 9; dv = 5 + p / 9; }
    else        { du = p - 36; dv = 4; }
    int o1 = du * 9 + dv, o2 = (8 - du) * 9 + (8 - dv);
    bool mir = !(du == 4 && dv == 4);
    for (int e = threadIdx.x; e < 4096; e += 256) {
      float s = 0.f;
#pragma unroll
      for (int kc = 0; kc < SK; ++kc)
        s += corrPart[((size_t)p * 16 + kc * 4 + n) * 4096 + e];
      int m = e >> 6, nn = e & 63;
      corrP[((size_t)(n * 64 + m) * 64 + nn) * CORR_RS + o1] = s;
      if (mir) corrP[((size_t)(n * 64 + nn) * 64 + m) * CORR_RS + o2] = s;
    }
    return;
  }
  // ---- xty ----
  int bid = bid0 - 164;          // ((n*CIN)+c)*COUT + b
  int b = bid & 3;
  int c = (bid >> 2) & 63;
  int n = bid >> 8;
  const float* xg = xs + (size_t)(n * CIN + c) * HWSZ;
  const float* yg = ys + (size_t)(n * COUT + b) * HWSZ;
  int tid = threadIdx.x;
  for (int i = tid; i < 100 * 100; i += 256) xp[i] = 0.f;
  __syncthreads();
  for (int i = tid; i < HWSZ; i += 256) {
    int h = i / 96, w = i - h * 96;
    xp[(h + 2) * 100 + (w + 2)] = xg[i];
  }
  __syncthreads();

  float acc[25];
#pragma unroll
  for (int k = 0; k < 25; ++k) acc[k] = 0.f;
  int tx = tid & 31, ty = tid >> 5;
  int w0 = tx * 3;
  for (int h = ty; h < 96; h += 8) {
    float y0 = yg[h * 96 + w0];
    float y1 = yg[h * 96 + w0 + 1];
    float y2 = yg[h * 96 + w0 + 2];
#pragma unroll
    for (int u = 0; u < 5; ++u) {
      const float* rowp = &xp[(h + u) * 100 + w0];
      float rbuf[7];
#pragma unroll
      for (int j = 0; j < 7; ++j) rbuf[j] = rowp[j];
#pragma unroll
      for (int v = 0; v < 5; ++v) {
        acc[u * 5 + v] += y0 * rbuf[v] + y1 * rbuf[v + 1] + y2 * rbuf[v + 2];
      }
    }
  }
  int wave = tid >> 6, lane = tid & 63;
#pragma unroll
  for (int k = 0; k < 25; ++k) {
    float s = waveAllSum(acc[k]);
    if (lane == 0) redbuf[wave][k] = s;
  }
  __syncthreads();
  if (tid < 25) {
    float tot = redbuf[0][tid] + redbuf[1][tid] + redbuf[2][tid] + redbuf[3][tid];
    float a = alpha[n] * reg[0] * ((float)(HH * WW) / (float)(DS * DS * CIN));
    float dvv = dd[((size_t)(n * COUT + b) * CIN + c) * 25 + tid];
    P[((size_t)(n * KD) + c * 25 + tid) * COUT + b] = tot + a * dvv;
  }
}

// ---------------- fused CG iteration (proven) ----------------
static __device__ __forceinline__ void allreduce2_f4(float4& a, float4& b,
                                                     float4* redA, float4* redB, int tid) {
#pragma unroll
  for (int off = 1; off < 64; off <<= 1) {
    a.x += __shfl_xor(a.x, off); a.y += __shfl_xor(a.y, off);
    a.z += __shfl_xor(a.z, off); a.w += __shfl_xor(a.w, off);
    b.x += __shfl_xor(b.x, off); b.y += __shfl_xor(b.y, off);
    b.z += __shfl_xor(b.z, off); b.w += __shfl_xor(b.w, off);
  }
  int wid = tid >> 6;
  if ((tid & 63) == 0) { redA[wid] = a; redB[wid] = b; }
  __syncthreads();
  float4 sa = f4add(f4add(redA[0], redA[1]), f4add(redA[2], redA[3]));
  float4 sb = f4add(f4add(redB[0], redB[1]), f4add(redB[2], redB[3]));
  __syncthreads();
  a = sa; b = sb;
}

__global__ __launch_bounds__(256) void cg_iter_kernel(
    const float* __restrict__ corrP, const float* __restrict__ P,
    const float* __restrict__ Rin, float* __restrict__ Rout,
    const float* __restrict__ Win, float* __restrict__ Wout,
    const float* __restrict__ PFin, float* __restrict__ PFout,
    float* __restrict__ X,
    const float* __restrict__ ralpha, const float* __restrict__ rreg,
    int first) {
  __shared__ float4 pS[KD];
  __shared__ float4 redA[4], redB[4];
  __shared__ float redW[4][25][4];

  int b = blockIdx.x;
  int n = b >> 6, c1 = b & 63;
  int tid = threadIdx.x;

  const float4* Rin4 = (const float4*)Rin + (size_t)n * KD;
  const float4* Win4 = (const float4*)Win + (size_t)n * KD;
  const float4* PFin4 = (const float4*)PFin + (size_t)n * KD;
  const float4* P4 = (const float4*)P + (size_t)n * KD;
  float4* Rout4 = (float4*)Rout + (size_t)n * KD;
  float4* PFout4 = (float4*)PFout + (size_t)n * KD;
  float4* X4 = (float4*)X + (size_t)n * KD;

  const float4 zero4 = make_float4(0.f, 0.f, 0.f, 0.f);
  float4 rv[7], wv[7], pv[7];
#pragma unroll
  for (int t = 0; t < 7; ++t) {
    int idx = tid + 256 * t;
    bool ok = idx < KD;
    if (first) {
      rv[t] = ok ? P4[idx] : zero4;
      wv[t] = zero4; pv[t] = zero4;
    } else {
      rv[t] = ok ? Rin4[idx] : zero4;
      wv[t] = ok ? Win4[idx] : zero4;
      pv[t] = ok ? PFin4[idx] : zero4;
    }
  }
  float4 rho_prev = zero4, pAp = zero4;
#pragma unroll
  for (int t = 0; t < 7; ++t) {
    rho_prev = f4fma(rv[t], rv[t], rho_prev);
    pAp = f4fma(pv[t], wv[t], pAp);
  }
  allreduce2_f4(rho_prev, pAp, redA, redB, tid);

  float4 av = first ? zero4 : f4div(rho_prev, pAp);

  float4 rho_k = zero4;
#pragma unroll
  for (int t = 0; t < 7; ++t) {
    rv[t] = f4sub(rv[t], f4mul(av, wv[t]));
    rho_k = f4fma(rv[t], rv[t], rho_k);
  }
  int lo = c1 * 25;
#pragma unroll
  for (int t = 0; t < 7; ++t) {
    int idx = tid + 256 * t;
    if (idx >= lo && idx < lo + 25) {
      if (first) X4[idx] = zero4;
      else X4[idx] = f4fma(av, pv[t], X4[idx]);
    }
  }
  float4 dummy = zero4;
  allreduce2_f4(rho_k, dummy, redA, redB, tid);

  float4 bv = first ? zero4 : f4div(rho_k, rho_prev);

#pragma unroll
  for (int t = 0; t < 7; ++t) {
    int idx = tid + 256 * t;
    if (idx < KD) {
      float4 pnew = f4fma(bv, pv[t], rv[t]);
      pS[idx] = pnew;
      if (idx >= lo && idx < lo + 25) {
        PFout4[idx] = pnew;
        Rout4[idx] = rv[t];
      }
    }
  }
  __syncthreads();

  int c2 = tid >> 2, col = tid & 3;
  const float4* crow4 = (const float4*)(corrP + (((size_t)(n * 64 + c1)) * 64 + c2) * CORR_RS);
  float creg[81];
#pragma unroll
  for (int t4 = 0; t4 < 20; ++t4) *(float4*)&creg[4 * t4] = crow4[t4];
  creg[80] = ((const float*)crow4)[80];

  float a25[25];
#pragma unroll
  for (int i = 0; i < 25; ++i) a25[i] = 0.f;
  const float* pSf = (const float*)pS;
#pragma unroll
  for (int j = 0; j < 25; ++j) {
    float pvv = pSf[(c2 * 25 + j) * 4 + col];
#pragma unroll
    for (int i = 0; i < 25; ++i) {
      const int i1 = i / 5, i2 = i % 5, j1 = j / 5, j2 = j % 5;
      a25[i] += creg[(j1 - i1 + 4) * 9 + (j2 - i2 + 4)] * pvv;
    }
  }
#pragma unroll
  for (int i = 0; i < 25; ++i) {
    float v = a25[i];
    v += __shfl_xor(v, 4); v += __shfl_xor(v, 8);
    v += __shfl_xor(v, 16); v += __shfl_xor(v, 32);
    a25[i] = v;
  }
  int wid = tid >> 6;
  if ((tid & 63) < 4) {
#pragma unroll
    for (int i = 0; i < 25; ++i) redW[wid][i][col] = a25[i];
  }
  __syncthreads();
  if (tid < 100) {
    int i = tid >> 2, cc = tid & 3;
    float wval = redW[0][i][cc] + redW[1][i][cc] + redW[2][i][cc] + redW[3][i][cc];
    float aa = ralpha[n] * rreg[0] * ((float)(HH * WW) / (float)(DS * DS * CIN));
    int row = lo + i;
    wval = fmaf(aa, pSf[row * 4 + cc], wval);
    Wout[((size_t)n * KD + row) * 4 + cc] = wval;
  }
}

// ---------------- finalize ----------------
__global__ __launch_bounds__(256) void cg_final_kernel(
    const float* __restrict__ Rin, const float* __restrict__ Win,
    const float* __restrict__ PFin, const float* __restrict__ X,
    float* __restrict__ out) {
  __shared__ float4 redA[4], redB[4];
  int b = blockIdx.x;
  int n = b >> 6, c1 = b & 63;
  int tid = threadIdx.x;

  const float4* Rin4 = (const float4*)Rin + (size_t)n * KD;
  const float4* Win4 = (const float4*)Win + (size_t)n * KD;
  const float4* PFin4 = (const float4*)PFin + (size_t)n * KD;
  const float4 zero4 = make_float4(0.f, 0.f, 0.f, 0.f);

  float4 rho = zero4, pAp = zero4;
#pragma unroll
  for (int t = 0; t < 7; ++t) {
    int idx = tid + 256 * t;
    if (idx < KD) {
      float4 r = Rin4[idx], w = Win4[idx], p = PFin4[idx];
      rho = f4fma(r, r, rho);
      pAp = f4fma(p, w, pAp);
    }
  }
  allreduce2_f4(rho, pAp, redA, redB, tid);
  float4 av = f4div(rho, pAp);

  if (tid < 100) {
    int i = tid >> 2, cc = tid & 3;
    int row = c1 * 25 + i;
    float a_cc = f4sel(av, cc);
    float xv = X[((size_t)n * KD + row) * 4 + cc] + a_cc * PFin[((size_t)n * KD + row) * 4 + cc];
    out[((size_t)(n * 4 + cc) * 64 + c1) * 25 + i] = xv;
  }
}

extern "C" void kernel_launch(void* const* d_in, const int* in_sizes, int n_in,
                              void* d_out, int out_size, void* d_ws, size_t ws_size,
                              hipStream_t stream) {
  (void)in_sizes; (void)n_in; (void)out_size; (void)ws_size;
  const float* xs    = (const float*)d_in[0];   // [4,1,64,96,96]
  const float* dd    = (const float*)d_in[1];   // [4,4,64,5,5]
  const float* ys    = (const float*)d_in[2];   // [4,4,1,96,96]
  const float* alpha = (const float*)d_in[3];   // [4]
  const float* reg   = (const float*)d_in[4];   // [1]
  float* out = (float*)d_out;
  float* ws  = (float*)d_ws;

  const size_t XELEM = (size_t)256 * 96 * ROWF;           // f16 per shift buffer
  const size_t XS_FLOATS = 5 * XELEM / 2;                 // 7,372,800 floats
  const size_t SZ_PART = (size_t)41 * 16 * 4096;          // 2,686,976 floats
  const size_t SZ_V = (size_t)NS * KD * COUT;             // 25,600 floats

  unsigned short* XS = (unsigned short*)ws;               // 29.5 MB (dead after corr_partial)
  float* corrP = ws;                                      // 5.5 MB, overlays dead XS
  float* corrPart = ws + XS_FLOATS;                       // 10.7 MB
  float* P   = corrPart + SZ_PART;
  float* X   = P + SZ_V;
  float* R0  = X + SZ_V;
  float* R1  = R0 + SZ_V;
  float* W0  = R1 + SZ_V;
  float* W1  = W0 + SZ_V;
  float* PF0 = W1 + SZ_V;
  float* PF1 = PF0 + SZ_V;
  float* Rb[2] = {R0, R1};
  float* Wb[2] = {W0, W1};
  float* Pb[2] = {PF0, PF1};

  convert_kernel<<<28800, 256, 0, stream>>>(xs, (unsigned int*)XS);
  corr_partial_kernel<<<41 * 16, 256, 0, stream>>>(XS, corrPart);
  reduce_xty_kernel<<<164 + NS * CIN * COUT, 256, 0, stream>>>(corrPart, corrP,
                                                               xs, ys, dd, alpha, reg, P);
  for (int k = 0; k < ITER; ++k) {
    cg_iter_kernel<<<NS * CIN, 256, 0, stream>>>(
        corrP, P,
        Rb[k & 1], Rb[(k + 1) & 1],
        Wb[k & 1], Wb[(k + 1) & 1],
        Pb[k & 1], Pb[(k + 1) & 1],
        X, alpha, reg, k == 0 ? 1 : 0);
  }
  cg_final_kernel<<<NS * CIN, 256, 0, stream>>>(Rb[ITER & 1], Wb[ITER & 1], Pb[ITER & 1], X, out);
}

// Round 10
// 150.173 us; speedup vs baseline: 17.4642x; 1.1018x over previous
//
#include <hip/hip_runtime.h>

// Problem constants
#define NS   4
#define CIN  64
#define COUT 4
#define HH   96
#define WW   96
#define HWSZ 9216
#define DS   5
#define KD   1600
#define ITER 7

// Tight f16 image geometry (5 shift buffers, 96 f16 per row)
#define TROWB 192                   // bytes per row (96 f16)
#define TCHB  (96*TROWB)            // per-channel bytes (18432)
#define TIMGB ((size_t)64*TCHB)     // per-sample bytes
#define TSB   ((size_t)256*TCHB)    // per-shift-buffer bytes (4,718,592)
#define CORR_RS 84                  // corr row stride in floats

#define SKC  12                     // kc chunks (8 B-rows each; 12*8 = 96 exact)
#define RB   8                      // B rows per block

// LDS band geometry: 24 row-slots (0..15 = A rows r0-4+s, 16..23 = B rows r0+j)
#define CSTR  104                   // channel stride bytes (26 dwords -> 2-way banks, free)
#define SLOTB (64*CSTR)             // 6656 B per row-slot; 24*6656 = 159744 <= 160 KiB

typedef _Float16 f16_t;
typedef _Float16 f16x8_t __attribute__((ext_vector_type(8)));
typedef float    f32x16_t __attribute__((ext_vector_type(16)));

static __device__ __forceinline__ float waveAllSum(float v) {
#pragma unroll
  for (int off = 32; off; off >>= 1) v += __shfl_xor(v, off);
  return v;
}
static __device__ __forceinline__ float4 f4add(float4 a, float4 b) {
  return make_float4(a.x + b.x, a.y + b.y, a.z + b.z, a.w + b.w);
}
static __device__ __forceinline__ float4 f4sub(float4 a, float4 b) {
  return make_float4(a.x - b.x, a.y - b.y, a.z - b.z, a.w - b.w);
}
static __device__ __forceinline__ float4 f4mul(float4 a, float4 b) {
  return make_float4(a.x * b.x, a.y * b.y, a.z * b.z, a.w * b.w);
}
static __device__ __forceinline__ float4 f4div(float4 a, float4 b) {
  return make_float4(a.x / b.x, a.y / b.y, a.z / b.z, a.w / b.w);
}
static __device__ __forceinline__ float4 f4fma(float4 a, float4 b, float4 c) {
  return make_float4(fmaf(a.x, b.x, c.x), fmaf(a.y, b.y, c.y),
                     fmaf(a.z, b.z, c.z), fmaf(a.w, b.w, c.w));
}
static __device__ __forceinline__ float f4sel(float4 v, int c) {
  return c == 0 ? v.x : c == 1 ? v.y : c == 2 ? v.z : v.w;
}

// ---------------- convert: xs fp32 -> 5 shifted tight f16 images ----------------
// TS_s[cg][r][j] = (j+s < 96) ? x[cg][r][j+s] : 0,  j in [0,96), s in 0..4.
__global__ __launch_bounds__(256) void convert_kernel(const float* __restrict__ xs,
                                                      unsigned int* __restrict__ TS32) {
  const int PER = 256 * 96 * 48;             // uints per shift buffer
  int idx = blockIdx.x * 256 + threadIdx.x;
  if (idx >= 5 * PER) return;
  int s = idx / PER;
  int rr = idx - s * PER;
  int p = rr % 48; int t = rr / 48;
  int r = t % 96;  int cg = t / 96;
  const float* row = xs + (size_t)cg * HWSZ + r * 96;
  int j0 = 2 * p, j1 = j0 + 1;
  float f0 = (j0 + s < 96) ? row[j0 + s] : 0.f;
  float f1 = (j1 + s < 96) ? row[j1 + s] : 0.f;
  f16_t h0 = (f16_t)f0, h1 = (f16_t)f1;
  unsigned int pk = (unsigned int)__builtin_bit_cast(unsigned short, h0)
                  | ((unsigned int)__builtin_bit_cast(unsigned short, h1) << 16);
  TS32[idx] = pk;
}

// ---------------- corr partial: band kernel with A-register ring ----------------
// Block = (n, sv=dv-4, kc); computes 9 du partial tiles over B rows [r0, r0+8).
// A = TS_0 rows [r0-4, r0+12) (invalid rows staged as zeros -> no compute guards).
// Per (kh, ktl) K-slice: slide B row with a 9-deep A-frag register ring:
// 2 LDS frag reads per 9 MFMA. Wave q owns C-quadrant (mt,nt). acc[9] = 144 VGPR.
__global__ __launch_bounds__(256, 1) void corr_partial_kernel(const unsigned short* __restrict__ TS,
                                                              float* __restrict__ corrPart) {
  __shared__ __align__(16) unsigned char lds[24 * SLOTB];   // 159744 B
  int bid = blockIdx.x;              // 240 = 4n * 5sv * 12kc
  int n = bid & 3;
  int rest = bid >> 2;
  int sv = rest % 5;
  int kc = rest / 5;
  int r0 = kc * RB;
  int tid = threadIdx.x, wid = tid >> 6, lane = tid & 63;
  int l5 = lane >> 5, l31 = lane & 31;
  int mt = wid >> 1, nt = wid & 1;

  const char* Abase = (const char*)TS + (size_t)n * TIMGB;                    // shift 0
  const char* Bbase = (const char*)TS + (size_t)sv * TSB + (size_t)n * TIMGB; // shift sv

  f32x16_t acc[9] = {};

  for (int kh = 0; kh < 2; ++kh) {
    if (kh) __syncthreads();                 // LDS reuse barrier
    // stage 24 slots * 64 ch * 96B (kh half) = 9216 16B-chunks; 36/thread in 3 batches
    for (int bb = 0; bb < 3; ++bb) {
      uint4 tmp[12];
#pragma unroll
      for (int i = 0; i < 12; ++i) {
        int q = (bb * 12 + i) * 256 + tid;
        int slot = q / 384;
        int rem = q - slot * 384;
        int ch = rem / 6, sub = rem - ch * 6;
        bool isA = slot < 16;
        int row = isA ? (r0 - 4 + slot) : (r0 + slot - 16);
        uint4 v = make_uint4(0u, 0u, 0u, 0u);
        if (row >= 0 && row < 96) {
          const char* src = (isA ? Abase : Bbase)
                          + (size_t)ch * TCHB + (size_t)row * TROWB + kh * 96 + sub * 16;
          v = *(const uint4*)src;
        }
        tmp[i] = v;
      }
#pragma unroll
      for (int i = 0; i < 12; ++i) {
        int q = (bb * 12 + i) * 256 + tid;
        int slot = q / 384;
        int rem = q - slot * 384;
        int ch = rem / 6, sub = rem - ch * 6;
        char* dst = (char*)lds + slot * SLOTB + ch * CSTR + sub * 16;
        *(uint2*)dst = make_uint2(tmp[i].x, tmp[i].y);         // 8B-aligned b64 pair
        *(uint2*)(dst + 8) = make_uint2(tmp[i].z, tmp[i].w);
      }
    }
    __syncthreads();

    int ca = mt * 32 + l31, cb = nt * 32 + l31;
#pragma unroll
    for (int ktl = 0; ktl < 3; ++ktl) {
      int ko = ktl * 32 + l5 * 16;
      auto frag = [&](int slot, int ch) -> f16x8_t {
        const char* p = (const char*)lds + slot * SLOTB + ch * CSTR + ko;
        uint2 lo = *(const uint2*)p;
        uint2 hi = *(const uint2*)(p + 8);
        uint4 u = make_uint4(lo.x, lo.y, hi.x, hi.y);
        return __builtin_bit_cast(f16x8_t, u);
      };
      f16x8_t ring[9];
#pragma unroll
      for (int t = 0; t < 9; ++t) ring[t] = frag(t, ca);       // A slots 0..8
#pragma unroll
      for (int r = 0; r < 8; ++r) {
        f16x8_t b = frag(16 + r, cb);                          // B row r0+r
#pragma unroll
        for (int du = 0; du < 9; ++du) {
          // A row = r0 + r + 4 - du  <->  slot r+8-du  <->  ring[(r+8-du)%9]
          acc[du] = __builtin_amdgcn_mfma_f32_32x32x16_f16(
              ring[(r + 8 - du) % 9], b, acc[du], 0, 0, 0);
        }
        if (r < 7) ring[r % 9] = frag(r + 9, ca);              // slide: load slot r+9
      }
    }
  }

  // write 9 partial tiles: corrPart[t=sv*9+du][kc][n][64*64]
#pragma unroll
  for (int du = 0; du < 9; ++du) {
    float* outp = corrPart + (((size_t)(sv * 9 + du) * SKC + kc) * 4 + n) * 4096;
#pragma unroll
    for (int rg = 0; rg < 16; ++rg) {
      int m  = mt * 32 + (rg & 3) + 8 * (rg >> 2) + 4 * l5;    // C/D row (m74/m101)
      int nn = nt * 32 + l31;
      outp[m * 64 + nn] = acc[du][rg];
    }
  }
}

// ---------------- fused: corr reduce (blocks 0..163) + xty (blocks 164..1187) ----------------
__global__ __launch_bounds__(256) void reduce_xty_kernel(const float* __restrict__ corrPart,
                                                         float* __restrict__ corrP,
                                                         const float* __restrict__ xs,
                                                         const float* __restrict__ ys,
                                                         const float* __restrict__ dd,
                                                         const float* __restrict__ alpha,
                                                         const float* __restrict__ reg,
                                                         float* __restrict__ P) {
  __shared__ float xp[100 * 100];
  __shared__ float redbuf[4][25];
  int bid0 = blockIdx.x;
  if (bid0 < 164) {
    // ---- corr reduce: sum SKC chunk partials, write main + mirror ----
    int n = bid0 / 41, p = bid0 % 41;
    int du, dv;
    if (p < 36) { du = p % 9; dv = 5 + p / 9; }
    else        { du = p - 36; dv = 4; }
    int t = (p < 36) ? (9 + p) : (p - 36);     // tile index sv*9+du
    int o1 = du * 9 + dv, o2 = (8 - du) * 9 + (8 - dv);
    bool mir = !(du == 4 && dv == 4);
    for (int e = threadIdx.x; e < 4096; e += 256) {
      float s = 0.f;
#pragma unroll
      for (int kc = 0; kc < SKC; ++kc)
        s += corrPart[(((size_t)t * SKC + kc) * 4 + n) * 4096 + e];
      int m = e >> 6, nn = e & 63;
      corrP[((size_t)(n * 64 + m) * 64 + nn) * CORR_RS + o1] = s;
      if (mir) corrP[((size_t)(n * 64 + nn) * 64 + m) * CORR_RS + o2] = s;
    }
    return;
  }
  // ---- xty ----
  int bid = bid0 - 164;          // ((n*CIN)+c)*COUT + b
  int b = bid & 3;
  int c = (bid >> 2) & 63;
  int n = bid >> 8;
  const float* xg = xs + (size_t)(n * CIN + c) * HWSZ;
  const float* yg = ys + (size_t)(n * COUT + b) * HWSZ;
  int tid = threadIdx.x;
  for (int i = tid; i < 100 * 100; i += 256) xp[i] = 0.f;
  __syncthreads();
  for (int i = tid; i < HWSZ; i += 256) {
    int h = i / 96, w = i - h * 96;
    xp[(h + 2) * 100 + (w + 2)] = xg[i];
  }
  __syncthreads();

  float acc[25];
#pragma unroll
  for (int k = 0; k < 25; ++k) acc[k] = 0.f;
  int tx = tid & 31, ty = tid >> 5;
  int w0 = tx * 3;
  for (int h = ty; h < 96; h += 8) {
    float y0 = yg[h * 96 + w0];
    float y1 = yg[h * 96 + w0 + 1];
    float y2 = yg[h * 96 + w0 + 2];
#pragma unroll
    for (int u = 0; u < 5; ++u) {
      const float* rowp = &xp[(h + u) * 100 + w0];
      float rbuf[7];
#pragma unroll
      for (int j = 0; j < 7; ++j) rbuf[j] = rowp[j];
#pragma unroll
      for (int v = 0; v < 5; ++v) {
        acc[u * 5 + v] += y0 * rbuf[v] + y1 * rbuf[v + 1] + y2 * rbuf[v + 2];
      }
    }
  }
  int wave = tid >> 6, lane = tid & 63;
#pragma unroll
  for (int k = 0; k < 25; ++k) {
    float s = waveAllSum(acc[k]);
    if (lane == 0) redbuf[wave][k] = s;
  }
  __syncthreads();
  if (tid < 25) {
    float tot = redbuf[0][tid] + redbuf[1][tid] + redbuf[2][tid] + redbuf[3][tid];
    float a = alpha[n] * reg[0] * ((float)(HH * WW) / (float)(DS * DS * CIN));
    float dvv = dd[((size_t)(n * COUT + b) * CIN + c) * 25 + tid];
    P[((size_t)(n * KD) + c * 25 + tid) * COUT + b] = tot + a * dvv;
  }
}

// ---------------- fused CG iteration (proven) ----------------
static __device__ __forceinline__ void allreduce2_f4(float4& a, float4& b,
                                                     float4* redA, float4* redB, int tid) {
#pragma unroll
  for (int off = 1; off < 64; off <<= 1) {
    a.x += __shfl_xor(a.x, off); a.y += __shfl_xor(a.y, off);
    a.z += __shfl_xor(a.z, off); a.w += __shfl_xor(a.w, off);
    b.x += __shfl_xor(b.x, off); b.y += __shfl_xor(b.y, off);
    b.z += __shfl_xor(b.z, off); b.w += __shfl_xor(b.w, off);
  }
  int wid = tid >> 6;
  if ((tid & 63) == 0) { redA[wid] = a; redB[wid] = b; }
  __syncthreads();
  float4 sa = f4add(f4add(redA[0], redA[1]), f4add(redA[2], redA[3]));
  float4 sb = f4add(f4add(redB[0], redB[1]), f4add(redB[2], redB[3]));
  __syncthreads();
  a = sa; b = sb;
}

__global__ __launch_bounds__(256) void cg_iter_kernel(
    const float* __restrict__ corrP, const float* __restrict__ P,
    const float* __restrict__ Rin, float* __restrict__ Rout,
    const float* __restrict__ Win, float* __restrict__ Wout,
    const float* __restrict__ PFin, float* __restrict__ PFout,
    float* __restrict__ X,
    const float* __restrict__ ralpha, const float* __restrict__ rreg,
    int first) {
  __shared__ float4 pS[KD];
  __shared__ float4 redA[4], redB[4];
  __shared__ float redW[4][25][4];

  int b = blockIdx.x;
  int n = b >> 6, c1 = b & 63;
  int tid = threadIdx.x;

  const float4* Rin4 = (const float4*)Rin + (size_t)n * KD;
  const float4* Win4 = (const float4*)Win + (size_t)n * KD;
  const float4* PFin4 = (const float4*)PFin + (size_t)n * KD;
  const float4* P4 = (const float4*)P + (size_t)n * KD;
  float4* Rout4 = (float4*)Rout + (size_t)n * KD;
  float4* PFout4 = (float4*)PFout + (size_t)n * KD;
  float4* X4 = (float4*)X + (size_t)n * KD;

  const float4 zero4 = make_float4(0.f, 0.f, 0.f, 0.f);
  float4 rv[7], wv[7], pv[7];
#pragma unroll
  for (int t = 0; t < 7; ++t) {
    int idx = tid + 256 * t;
    bool ok = idx < KD;
    if (first) {
      rv[t] = ok ? P4[idx] : zero4;
      wv[t] = zero4; pv[t] = zero4;
    } else {
      rv[t] = ok ? Rin4[idx] : zero4;
      wv[t] = ok ? Win4[idx] : zero4;
      pv[t] = ok ? PFin4[idx] : zero4;
    }
  }
  float4 rho_prev = zero4, pAp = zero4;
#pragma unroll
  for (int t = 0; t < 7; ++t) {
    rho_prev = f4fma(rv[t], rv[t], rho_prev);
    pAp = f4fma(pv[t], wv[t], pAp);
  }
  allreduce2_f4(rho_prev, pAp, redA, redB, tid);

  float4 av = first ? zero4 : f4div(rho_prev, pAp);

  float4 rho_k = zero4;
#pragma unroll
  for (int t = 0; t < 7; ++t) {
    rv[t] = f4sub(rv[t], f4mul(av, wv[t]));
    rho_k = f4fma(rv[t], rv[t], rho_k);
  }
  int lo = c1 * 25;
#pragma unroll
  for (int t = 0; t < 7; ++t) {
    int idx = tid + 256 * t;
    if (idx >= lo && idx < lo + 25) {
      if (first) X4[idx] = zero4;
      else X4[idx] = f4fma(av, pv[t], X4[idx]);
    }
  }
  float4 dummy = zero4;
  allreduce2_f4(rho_k, dummy, redA, redB, tid);

  float4 bv = first ? zero4 : f4div(rho_k, rho_prev);

#pragma unroll
  for (int t = 0; t < 7; ++t) {
    int idx = tid + 256 * t;
    if (idx < KD) {
      float4 pnew = f4fma(bv, pv[t], rv[t]);
      pS[idx] = pnew;
      if (idx >= lo && idx < lo + 25) {
        PFout4[idx] = pnew;
        Rout4[idx] = rv[t];
      }
    }
  }
  __syncthreads();

  int c2 = tid >> 2, col = tid & 3;
  const float4* crow4 = (const float4*)(corrP + (((size_t)(n * 64 + c1)) * 64 + c2) * CORR_RS);
  float creg[81];
#pragma unroll
  for (int t4 = 0; t4 < 20; ++t4) *(float4*)&creg[4 * t4] = crow4[t4];
  creg[80] = ((const float*)crow4)[80];

  float a25[25];
#pragma unroll
  for (int i = 0; i < 25; ++i) a25[i] = 0.f;
  const float* pSf = (const float*)pS;
#pragma unroll
  for (int j = 0; j < 25; ++j) {
    float pvv = pSf[(c2 * 25 + j) * 4 + col];
#pragma unroll
    for (int i = 0; i < 25; ++i) {
      const int i1 = i / 5, i2 = i % 5, j1 = j / 5, j2 = j % 5;
      a25[i] += creg[(j1 - i1 + 4) * 9 + (j2 - i2 + 4)] * pvv;
    }
  }
#pragma unroll
  for (int i = 0; i < 25; ++i) {
    float v = a25[i];
    v += __shfl_xor(v, 4); v += __shfl_xor(v, 8);
    v += __shfl_xor(v, 16); v += __shfl_xor(v, 32);
    a25[i] = v;
  }
  int wid = tid >> 6;
  if ((tid & 63) < 4) {
#pragma unroll
    for (int i = 0; i < 25; ++i) redW[wid][i][col] = a25[i];
  }
  __syncthreads();
  if (tid < 100) {
    int i = tid >> 2, cc = tid & 3;
    float wval = redW[0][i][cc] + redW[1][i][cc] + redW[2][i][cc] + redW[3][i][cc];
    float aa = ralpha[n] * rreg[0] * ((float)(HH * WW) / (float)(DS * DS * CIN));
    int row = lo + i;
    wval = fmaf(aa, pSf[row * 4 + cc], wval);
    Wout[((size_t)n * KD + row) * 4 + cc] = wval;
  }
}

// ---------------- finalize ----------------
__global__ __launch_bounds__(256) void cg_final_kernel(
    const float* __restrict__ Rin, const float* __restrict__ Win,
    const float* __restrict__ PFin, const float* __restrict__ X,
    float* __restrict__ out) {
  __shared__ float4 redA[4], redB[4];
  int b = blockIdx.x;
  int n = b >> 6, c1 = b & 63;
  int tid = threadIdx.x;

  const float4* Rin4 = (const float4*)Rin + (size_t)n * KD;
  const float4* Win4 = (const float4*)Win + (size_t)n * KD;
  const float4* PFin4 = (const float4*)PFin + (size_t)n * KD;
  const float4 zero4 = make_float4(0.f, 0.f, 0.f, 0.f);

  float4 rho = zero4, pAp = zero4;
#pragma unroll
  for (int t = 0; t < 7; ++t) {
    int idx = tid + 256 * t;
    if (idx < KD) {
      float4 r = Rin4[idx], w = Win4[idx], p = PFin4[idx];
      rho = f4fma(r, r, rho);
      pAp = f4fma(p, w, pAp);
    }
  }
  allreduce2_f4(rho, pAp, redA, redB, tid);
  float4 av = f4div(rho, pAp);

  if (tid < 100) {
    int i = tid >> 2, cc = tid & 3;
    int row = c1 * 25 + i;
    float a_cc = f4sel(av, cc);
    float xv = X[((size_t)n * KD + row) * 4 + cc] + a_cc * PFin[((size_t)n * KD + row) * 4 + cc];
    out[((size_t)(n * 4 + cc) * 64 + c1) * 25 + i] = xv;
  }
}

extern "C" void kernel_launch(void* const* d_in, const int* in_sizes, int n_in,
                              void* d_out, int out_size, void* d_ws, size_t ws_size,
                              hipStream_t stream) {
  (void)in_sizes; (void)n_in; (void)out_size; (void)ws_size;
  const float* xs    = (const float*)d_in[0];   // [4,1,64,96,96]
  const float* dd    = (const float*)d_in[1];   // [4,4,64,5,5]
  const float* ys    = (const float*)d_in[2];   // [4,4,1,96,96]
  const float* alpha = (const float*)d_in[3];   // [4]
  const float* reg   = (const float*)d_in[4];   // [1]
  float* out = (float*)d_out;
  float* ws  = (float*)d_ws;

  const size_t TS_FLOATS = 5 * TSB / 4;                   // 5,898,240 floats (23.6 MB)
  const size_t SZ_PART = (size_t)45 * SKC * 4 * 4096;     // 8,847,360 floats (35.4 MB)
  const size_t SZ_V = (size_t)NS * KD * COUT;             // 25,600 floats

  unsigned short* TS = (unsigned short*)ws;               // dead after corr_partial
  float* corrP = ws;                                      // 5.5 MB, overlays dead TS
  float* corrPart = ws + TS_FLOATS;
  float* P   = corrPart + SZ_PART;
  float* X   = P + SZ_V;
  float* R0  = X + SZ_V;
  float* R1  = R0 + SZ_V;
  float* W0  = R1 + SZ_V;
  float* W1  = W0 + SZ_V;
  float* PF0 = W1 + SZ_V;
  float* PF1 = PF0 + SZ_V;
  float* Rb[2] = {R0, R1};
  float* Wb[2] = {W0, W1};
  float* Pb[2] = {PF0, PF1};

  convert_kernel<<<23040, 256, 0, stream>>>(xs, (unsigned int*)TS);
  corr_partial_kernel<<<240, 256, 0, stream>>>(TS, corrPart);
  reduce_xty_kernel<<<164 + NS * CIN * COUT, 256, 0, stream>>>(corrPart, corrP,
                                                               xs, ys, dd, alpha, reg, P);
  for (int k = 0; k < ITER; ++k) {
    cg_iter_kernel<<<NS * CIN, 256, 0, stream>>>(
        corrP, P,
        Rb[k & 1], Rb[(k + 1) & 1],
        Wb[k & 1], Wb[(k + 1) & 1],
        Pb[k & 1], Pb[(k + 1) & 1],
        X, alpha, reg, k == 0 ? 1 : 0);
  }
  cg_final_kernel<<<NS * CIN, 256, 0, stream>>>(Rb[ITER & 1], Wb[ITER & 1], Pb[ITER & 1], X, out);
}